// Round 2
// baseline (189.535 us; speedup 1.0000x reference)
//
#include <hip/hip_runtime.h>
#include <hip/hip_bf16.h>

// Established rounds 0-10: inputs fp32 (detector=insurance), output fp32.
// R5/R6: VALU->MFMA. R7: attn 128-wide s-tiles. R8: fold -> MFMA. R10
// LESSON: register prefetch before a __syncthreads is DEFEATED (barrier
// emits s_waitcnt vmcnt(0)). R11: direct stage->LDS, 128x64 tiles for TLP.
// R12: swapped-QK attn (S^T = mfma(K,Q)): lane-local softmax, no qls,
// exp2-domain, exact rescale-skip. 55->44us but Ps round-trip (stride 72dw
// = 8 mod 32) was the REAL conflict source: 4-way on b64 writes AND b128
// reads within quarter-waves -> conflicts 4.5M->7.2M.
// R13 (this round): kill Ps entirely. PV contraction order over s is
// arbitrary if A and B agree -> permute V's s-slots in LDS (sigma: bits
// slot[1:0]=s[1:0], slot[2]=s[4], slot[3]=s[2], slot[4]=s[3]) so the PV
// A-operand packs DIRECTLY from the lane's own Sc registers (16 pack2).
// Saves 12 LDS ops/wave-iter + all Ps conflicts + 18KB LDS ->
// launch_bounds(256,4), all 4 grid-blocks/CU resident.
#define B_  2
#define T_  2048
#define D_  1024
#define H_  16
#define DH_ 64
#define R_  32
#define BT_ (B_*T_)          // 4096
#define BH_ (B_*H_)          // 32

typedef unsigned short u16;
typedef unsigned int   u32;
typedef __attribute__((ext_vector_type(8))) short bhalf8;   // 8 bf16 = 4 VGPRs
typedef __attribute__((ext_vector_type(4))) float floatx4;  // MFMA C/D

// Workspace layout (bytes). Total ~38 MB.
#define WSB_FLAG  0
#define WSB_XB    256                        // bf16 x     (4096,1024)  8 MB
#define WSB_WCATT (WSB_XB    + 8388608)      // bf16 WcatT (2048,1024)  4 MB
#define WSB_QL    (WSB_WCATT + 4194304)      // bf16 (B,H,T,R)          4 MB
#define WSB_KL    (WSB_QL    + 4194304)      // bf16 (B,H,T,R)          4 MB
#define WSB_VT    (WSB_KL    + 4194304)      // bf16 (B,H,DH,T)         8 MB
#define WSB_YB    (WSB_VT    + 8388608)      // bf16 y     (B,T,D)      8 MB
#define WSB_WOT   (WSB_YB    + 8388608)      // bf16 WoT   (1024,1024)  2 MB

#define NEG_ -1.0e30f

__device__ __forceinline__ float bfs(u16 s) {
    union { u32 i; float f; } w; w.i = ((u32)s) << 16; return w.f;
}
__device__ __forceinline__ u16 tob(float f) {
    __hip_bfloat16 h = __float2bfloat16(f);   // RNE
    return *(u16*)&h;
}
__device__ __forceinline__ u32 pack2(float a, float b) {
    return (u32)tob(a) | ((u32)tob(b) << 16);
}

// ---------------------------------------------------------------------------
// Kernel D: detect input dtype (1 = bf16, 0 = fp32) — insurance only.
// ---------------------------------------------------------------------------
__global__ __launch_bounds__(64) void detect_dtype(const u32* __restrict__ xw,
                                                   int* __restrict__ flag)
{
    const int tid = threadIdx.x;
    int hits = 0;
    for (int i = tid; i < 512; i += 64) {
        const u32 w = xw[i];
        const u32 h = w & 0xFFFFu;
        const u32 e = (h >> 7) & 0xFFu;
        if (h == 0u || (e >= 100u && e <= 150u)) ++hits;
    }
    #pragma unroll
    for (int off = 32; off; off >>= 1) hits += __shfl_down(hits, off, 64);
    if (tid == 0) *flag = (hits >= 300) ? 1 : 0;
}

// ---------------------------------------------------------------------------
// Kernel C: x -> xb bf16 (8 elems/thread). HBM-bound, ~24 MB traffic.
// ---------------------------------------------------------------------------
__global__ __launch_bounds__(256) void convert_x(
    const void* __restrict__ x, u16* __restrict__ xb,
    const int* __restrict__ flag)
{
    const int isbf = *flag;
    const int e = blockIdx.x * 256 + threadIdx.x;  // over 524288 (x8 elems)
    if (isbf) {
        ((uint4*)xb)[e] = ((const uint4*)x)[e];
    } else {
        float4 a0 = ((const float4*)x)[2*e];
        float4 a1 = ((const float4*)x)[2*e + 1];
        uint4 o;
        o.x = pack2(a0.x, a0.y); o.y = pack2(a0.z, a0.w);
        o.z = pack2(a1.x, a1.y); o.w = pack2(a1.z, a1.w);
        ((uint4*)xb)[e] = o;
    }
}

// ---------------------------------------------------------------------------
// Kernel 0: fold via MFMA. Per head h: Cq(32x1024) = Aq_h^T(32x64) @ Wq_h(64x1024)
// with m=r, k=dh, n=d. B operand (Wqkv slice) is k-contiguous natively.
// Scale folds 1/sqrt(32) * log2(e) so attn softmax uses native exp2.
// ---------------------------------------------------------------------------
__global__ __launch_bounds__(256) void fold_mfma(
    const void* __restrict__ Wqkv, const void* __restrict__ Wq_lsr,
    const void* __restrict__ Wk_lsr, const void* __restrict__ core,
    u16* __restrict__ WcatT, const int* __restrict__ flag)
{
    __shared__ __align__(16) u16 Bq[128 * 72];   // [n=d][k=dh]
    __shared__ __align__(16) u16 Bk[128 * 72];
    __shared__ __align__(16) u16 Aq[32 * 72];    // [m=r][k=dh]
    __shared__ __align__(16) u16 Ak[32 * 72];
    const int isbf = *flag;
    const int tid  = threadIdx.x;
    const int lane = tid & 63;
    const int w    = tid >> 6;
    const int n16  = lane & 15;
    const int q4   = lane >> 4;
    const int h    = blockIdx.y;        // 0..15
    const int d0   = blockIdx.x * 128;  // 0..896

    #pragma unroll
    for (int p = 0; p < 8; ++p) {
        const int e  = tid + p * 256;
        const int r  = e & 31, dh = e >> 5;
        float aq, ak;
        if (isbf) {
            aq = bfs(((const u16*)Wq_lsr)[(h*DH_ + dh)*R_ + r]);
            ak = bfs(((const u16*)Wk_lsr)[(h*DH_ + dh)*R_ + r]);
        } else {
            aq = ((const float*)Wq_lsr)[(h*DH_ + dh)*R_ + r];
            ak = ((const float*)Wk_lsr)[(h*DH_ + dh)*R_ + r];
        }
        Aq[r * 72 + dh] = tob(aq);
        Ak[r * 72 + dh] = tob(ak);
    }
    #pragma unroll
    for (int p = 0; p < 8; ++p) {
        const int e  = tid + p * 256;      // 0..2047
        const int n  = e >> 4, ch = e & 15;
        if (isbf) {
            uint2 wq = *(const uint2*)((const u16*)Wqkv + (size_t)(d0+n)*(3*D_) + h*DH_ + ch*4);
            uint2 wk = *(const uint2*)((const u16*)Wqkv + (size_t)(d0+n)*(3*D_) + D_ + h*DH_ + ch*4);
            *(uint2*)&Bq[n * 72 + ch*4] = wq;
            *(uint2*)&Bk[n * 72 + ch*4] = wk;
        } else {
            float4 fq = *(const float4*)((const float*)Wqkv + (size_t)(d0+n)*(3*D_) + h*DH_ + ch*4);
            float4 fk = *(const float4*)((const float*)Wqkv + (size_t)(d0+n)*(3*D_) + D_ + h*DH_ + ch*4);
            uint2 oq, ok;
            oq.x = pack2(fq.x, fq.y); oq.y = pack2(fq.z, fq.w);
            ok.x = pack2(fk.x, fk.y); ok.y = pack2(fk.z, fk.w);
            *(uint2*)&Bq[n * 72 + ch*4] = oq;
            *(uint2*)&Bk[n * 72 + ch*4] = ok;
        }
    }
    __syncthreads();

    floatx4 accq[2][2], acck[2][2];
    #pragma unroll
    for (int mi = 0; mi < 2; ++mi)
        #pragma unroll
        for (int ni = 0; ni < 2; ++ni) { accq[mi][ni] = (floatx4)(0.f); acck[mi][ni] = (floatx4)(0.f); }

    #pragma unroll
    for (int kk = 0; kk < 2; ++kk) {
        bhalf8 aqf[2], akf[2], bqf[2], bkf[2];
        #pragma unroll
        for (int mi = 0; mi < 2; ++mi) {
            aqf[mi] = *(const bhalf8*)&Aq[(mi*16 + n16) * 72 + kk*32 + q4*8];
            akf[mi] = *(const bhalf8*)&Ak[(mi*16 + n16) * 72 + kk*32 + q4*8];
        }
        #pragma unroll
        for (int ni = 0; ni < 2; ++ni) {
            bqf[ni] = *(const bhalf8*)&Bq[(w*32 + ni*16 + n16) * 72 + kk*32 + q4*8];
            bkf[ni] = *(const bhalf8*)&Bk[(w*32 + ni*16 + n16) * 72 + kk*32 + q4*8];
        }
        #pragma unroll
        for (int mi = 0; mi < 2; ++mi)
            #pragma unroll
            for (int ni = 0; ni < 2; ++ni) {
                accq[mi][ni] = __builtin_amdgcn_mfma_f32_16x16x32_bf16(aqf[mi], bqf[ni], accq[mi][ni], 0, 0, 0);
                acck[mi][ni] = __builtin_amdgcn_mfma_f32_16x16x32_bf16(akf[mi], bkf[ni], acck[mi][ni], 0, 0, 0);
            }
    }

    // 1/sqrt(32) * log2(e): softmax done in exp2 domain (native v_exp_f32).
    const float scale = (float)(0.17677669529663687 * 1.4426950408889634);
    #pragma unroll
    for (int mi = 0; mi < 2; ++mi) {
        #pragma unroll
        for (int rr = 0; rr < 4; ++rr) {
            const int r = mi*16 + q4*4 + rr;
            const float cc = (isbf ? bfs(((const u16*)core)[h*R_ + r])
                                   : ((const float*)core)[h*R_ + r]) * scale;
            #pragma unroll
            for (int ni = 0; ni < 2; ++ni) {
                const int d = d0 + w*32 + ni*16 + n16;
                WcatT[(size_t)(h*R_ + r) * D_ + d]       = tob(accq[mi][ni][rr] * cc);
                WcatT[(size_t)(512 + h*R_ + r) * D_ + d] = tob(acck[mi][ni][rr]);
            }
        }
    }
}

// ---------------------------------------------------------------------------
// Kernel T: generic transposing convert (fp32/bf16 -> bf16), 64x64 tiles.
// ---------------------------------------------------------------------------
__global__ __launch_bounds__(256) void convert_T(
    const void* __restrict__ src, u16* __restrict__ dst,
    int srcStride, int srcColOff, int dstRowOff, const int* __restrict__ flag)
{
    __shared__ __align__(16) u16 tile[64 * 72];
    const int isbf = *flag;
    const int tid = threadIdx.x;
    const int j0  = blockIdx.x * 64;
    const int i0  = blockIdx.y * 64;
    #pragma unroll
    for (int p = 0; p < 2; ++p) {
        const int e = tid + p * 256;
        const int r = e >> 3, ch = e & 7;
        if (isbf) {
            uint4 w = *(const uint4*)((const u16*)src + (size_t)(i0 + r) * srcStride + srcColOff + j0 + ch*8);
            *(uint4*)&tile[r * 72 + ch*8] = w;
        } else {
            const float* s = (const float*)src + (size_t)(i0 + r) * srcStride + srcColOff + j0 + ch*8;
            float4 a0 = *(const float4*)s;
            float4 a1 = *(const float4*)(s + 4);
            uint4 o;
            o.x = pack2(a0.x, a0.y); o.y = pack2(a0.z, a0.w);
            o.z = pack2(a1.x, a1.y); o.w = pack2(a1.z, a1.w);
            *(uint4*)&tile[r * 72 + ch*8] = o;
        }
    }
    __syncthreads();
    #pragma unroll
    for (int p = 0; p < 2; ++p) {
        const int e = tid + p * 256;
        const int c = e >> 3, ch = e & 7;
        u16 tmp[8];
        #pragma unroll
        for (int j = 0; j < 8; ++j) tmp[j] = tile[(ch*8 + j) * 72 + c];
        *(uint4*)(dst + (size_t)(dstRowOff + j0 + c) * D_ + i0 + ch*8) = *(uint4*)tmp;
    }
}

// ---------------------------------------------------------------------------
// Kernel 1: MFMA gemm1  xb(4096,1024) @ WcatT^T -> ql/kl + v_t.
// 128x64 tile, BK=64, 4 waves 2x2 (wave = 64m x 32n, acc[4][2]).
// Grid (32 bn, 32 bm) = 1024 blocks = 4/CU: TLP hides the barrier drain.
// ---------------------------------------------------------------------------
__global__ __launch_bounds__(256) void gemm1_mfma(
    const u16* __restrict__ xb, const u16* __restrict__ WcatT,
    u16* __restrict__ ql, u16* __restrict__ kl, u16* __restrict__ v_t)
{
    __shared__ __align__(16) u16 As[128 * 72];   // 18432 B
    __shared__ __align__(16) u16 Bs[64 * 72];    //  9216 B
    const int tid  = threadIdx.x;
    const int lane = tid & 63;
    const int w    = tid >> 6;
    const int n16  = lane & 15;
    const int q4   = lane >> 4;
    const int wx   = w & 1;          // n-half (32 cols)
    const int wy   = w >> 1;         // m-half (64 rows)
    const int bm   = blockIdx.y * 128;
    const int bn   = blockIdx.x * 64;

    floatx4 acc[4][2];
    #pragma unroll
    for (int i = 0; i < 4; ++i)
        #pragma unroll
        for (int j = 0; j < 2; ++j) acc[i][j] = (floatx4)(0.f);

    for (int kt = 0; kt < D_; kt += 64) {
        #pragma unroll
        for (int p = 0; p < 4; ++p) {
            const int e = tid + p * 256;       // 0..1023
            const int r = e >> 3, ch = (e & 7) * 8;
            *(uint4*)&As[r * 72 + ch] = *(const uint4*)(xb + (size_t)(bm + r) * D_ + kt + ch);
        }
        #pragma unroll
        for (int p = 0; p < 2; ++p) {
            const int e = tid + p * 256;       // 0..511
            const int r = e >> 3, ch = (e & 7) * 8;
            *(uint4*)&Bs[r * 72 + ch] = *(const uint4*)(WcatT + (size_t)(bn + r) * D_ + kt + ch);
        }
        __syncthreads();
        #pragma unroll
        for (int kk = 0; kk < 2; ++kk) {
            bhalf8 a[4], b[2];
            #pragma unroll
            for (int mi = 0; mi < 4; ++mi)
                a[mi] = *(const bhalf8*)&As[(wy*64 + mi*16 + n16) * 72 + kk*32 + q4*8];
            #pragma unroll
            for (int ni = 0; ni < 2; ++ni)
                b[ni] = *(const bhalf8*)&Bs[(wx*32 + ni*16 + n16) * 72 + kk*32 + q4*8];
            #pragma unroll
            for (int mi = 0; mi < 4; ++mi)
                #pragma unroll
                for (int ni = 0; ni < 2; ++ni)
                    acc[mi][ni] = __builtin_amdgcn_mfma_f32_16x16x32_bf16(
                        a[mi], b[ni], acc[mi][ni], 0, 0, 0);
        }
        __syncthreads();
    }

    if (bn < 1024) {
        #pragma unroll
        for (int mi = 0; mi < 4; ++mi) {
            #pragma unroll
            for (int rr = 0; rr < 4; ++rr) {
                const int row = bm + wy*64 + mi*16 + q4*4 + rr;
                const int b   = row >> 11;
                const int t   = row & (T_ - 1);
                #pragma unroll
                for (int ni = 0; ni < 2; ++ni) {
                    const int col = bn + wx*32 + ni*16 + n16;
                    const u16 val = tob(acc[mi][ni][rr]);
                    if (col < 512) {
                        const int h = col >> 5, r = col & 31;
                        ql[((size_t)(b*H_ + h)*T_ + t)*R_ + r] = val;
                    } else {
                        const int c = col - 512; const int h = c >> 5, r = c & 31;
                        kl[((size_t)(b*H_ + h)*T_ + t)*R_ + r] = val;
                    }
                }
            }
        }
    } else {
        // v: write v_t (B,H,DH,T) directly — 4 consecutive t pack into 8B
        #pragma unroll
        for (int mi = 0; mi < 4; ++mi) {
            const int row0 = bm + wy*64 + mi*16 + q4*4;
            const int b = row0 >> 11;
            const int t = row0 & (T_ - 1);
            #pragma unroll
            for (int ni = 0; ni < 2; ++ni) {
                const int c = bn - 1024 + wx*32 + ni*16 + n16;
                const int h = c >> 6, dh = c & 63;
                uint2 o;
                o.x = pack2(acc[mi][ni][0], acc[mi][ni][1]);
                o.y = pack2(acc[mi][ni][2], acc[mi][ni][3]);
                *(uint2*)(v_t + ((size_t)(b*H_ + h) * DH_ + dh) * T_ + t) = o;
            }
        }
    }
}

// ---------------------------------------------------------------------------
// Kernel 2 (R13): swapped-QK flash attention, zero-LDS P path.
// S^T = mfma(K,Q): lane owns q=n16, s = 16c+4q4+r in regs. PV A-frag packs
// DIRECTLY from the lane's own registers; V is staged into LDS with
// sigma-permuted s-slots (slot[1:0]=s[1:0], slot[2]=s[4], slot[3]=s[2],
// slot[4]=s[3]) so the natural b128 B-frag read at slot 32kc+8q4+j yields
// V[s(kc,q4,j)][d] matching the A-side order. No Ps. LDS 27.6KB.
// ---------------------------------------------------------------------------
__global__ __launch_bounds__(256, 4) void attn_kernel(
    const u16* __restrict__ ql, const u16* __restrict__ kl,
    const u16* __restrict__ v_t, u16* __restrict__ y)
{
    __shared__ __align__(16) u16 kls[128 * 40];      // 10240 B
    __shared__ __align__(16) u16 vsT[64 * 136];      // 17408 B, sigma-permuted

    const int tid  = threadIdx.x;
    const int lane = tid & 63;
    const int w    = tid >> 6;
    const int n16  = lane & 15;
    const int q4   = lane >> 4;
    const int bh   = blockIdx.x;
    const int qt   = 31 - (int)blockIdx.y;   // heavy q-tiles first
    const int t0   = qt * 64;
    const int nt   = (qt + 2) >> 1;          // # of 128-wide s-tiles

    // Q fragment = B-operand of swapped QK^T; loads directly in frag layout.
    const u16* qlb = ql + (size_t)bh * T_ * R_;
    const bhalf8 aq = *(const bhalf8*)(qlb + (size_t)(t0 + w*16 + n16) * R_ + q4*8);

    const u16* klb = kl  + (size_t)bh * T_ * R_;
    const u16* vtb = v_t + (size_t)bh * DH_ * T_;
    const int rk = tid >> 2, ck = (tid & 3) * 8;
    const int dv = tid >> 4;
    const int m  = tid & 15;
    const int cv = m * 8;
    // sigma staging base: 8 consecutive s (=8m+i) -> two uint2 at pb, pb+8.
    const int pb = ((m & 1) << 4) | (((m >> 1) & 1) << 2) | ((m >> 2) << 5);

    uint4 kc0 = *(const uint4*)(klb + (size_t)(rk     ) * R_ + ck);
    uint4 kc1 = *(const uint4*)(klb + (size_t)(rk + 64) * R_ + ck);
    uint4 vc0 = *(const uint4*)(vtb + (size_t)(dv     ) * T_ + cv);
    uint4 vc1 = *(const uint4*)(vtb + (size_t)(dv + 16) * T_ + cv);
    uint4 vc2 = *(const uint4*)(vtb + (size_t)(dv + 32) * T_ + cv);
    uint4 vc3 = *(const uint4*)(vtb + (size_t)(dv + 48) * T_ + cv);
    uint4 kn0 = kc0, kn1 = kc1, vn0 = vc0, vn1 = vc1, vn2 = vc2, vn3 = vc3;

    float mrow = NEG_, lrow = 0.f;           // one q-row per lane
    floatx4 O[4];
    #pragma unroll
    for (int c = 0; c < 4; ++c) O[c] = (floatx4)(0.f);

    for (int it = 0; it < nt; ++it) {
        const int s0 = it * 128;
        __syncthreads();
        *(uint4*)&kls[(rk     ) * 40 + ck] = kc0;
        *(uint4*)&kls[(rk + 64) * 40 + ck] = kc1;
        {
            uint2 t;
            t.x = vc0.x; t.y = vc0.y; *(uint2*)&vsT[(dv     ) * 136 + pb    ] = t;
            t.x = vc0.z; t.y = vc0.w; *(uint2*)&vsT[(dv     ) * 136 + pb + 8] = t;
            t.x = vc1.x; t.y = vc1.y; *(uint2*)&vsT[(dv + 16) * 136 + pb    ] = t;
            t.x = vc1.z; t.y = vc1.w; *(uint2*)&vsT[(dv + 16) * 136 + pb + 8] = t;
            t.x = vc2.x; t.y = vc2.y; *(uint2*)&vsT[(dv + 32) * 136 + pb    ] = t;
            t.x = vc2.z; t.y = vc2.w; *(uint2*)&vsT[(dv + 32) * 136 + pb + 8] = t;
            t.x = vc3.x; t.y = vc3.y; *(uint2*)&vsT[(dv + 48) * 136 + pb    ] = t;
            t.x = vc3.z; t.y = vc3.w; *(uint2*)&vsT[(dv + 48) * 136 + pb + 8] = t;
        }
        if (it + 1 < nt) {
            const int s1 = s0 + 128;
            kn0 = *(const uint4*)(klb + (size_t)(s1 + rk     ) * R_ + ck);
            kn1 = *(const uint4*)(klb + (size_t)(s1 + rk + 64) * R_ + ck);
            vn0 = *(const uint4*)(vtb + (size_t)(dv     ) * T_ + s1 + cv);
            vn1 = *(const uint4*)(vtb + (size_t)(dv + 16) * T_ + s1 + cv);
            vn2 = *(const uint4*)(vtb + (size_t)(dv + 32) * T_ + s1 + cv);
            vn3 = *(const uint4*)(vtb + (size_t)(dv + 48) * T_ + s1 + cv);
        }
        __syncthreads();

        // S^T: A = K-frag (m=s), B = Q-frag (n=q). Lane: q=n16, s=16c+4q4+r.
        floatx4 Sc[8];
        #pragma unroll
        for (int c = 0; c < 8; ++c) {
            bhalf8 ak = *(const bhalf8*)&kls[(16*c + n16) * 40 + q4*8];
            Sc[c] = __builtin_amdgcn_mfma_f32_16x16x32_bf16(ak, aq, (floatx4)(0.f), 0, 0, 0);
        }

        if (it == nt - 1) {
            const int tq = w*16 + n16;                 // local q row
            #pragma unroll
            for (int c = 0; c < 8; ++c) {
                const int sb = s0 - t0 + 16*c + 4*q4;  // local s base
                #pragma unroll
                for (int r = 0; r < 4; ++r)
                    if (sb + r > tq) Sc[c][r] = NEG_;
            }
        }

        // lane-local row max over 32 values + cross-q4 combine (2 shuffles)
        float cmax[8];
        #pragma unroll
        for (int c = 0; c < 8; ++c)
            cmax[c] = fmaxf(fmaxf(Sc[c][0], Sc[c][1]), fmaxf(Sc[c][2], Sc[c][3]));
        float rmax = fmaxf(fmaxf(fmaxf(cmax[0], cmax[1]), fmaxf(cmax[2], cmax[3])),
                           fmaxf(fmaxf(cmax[4], cmax[5]), fmaxf(cmax[6], cmax[7])));
        rmax = fmaxf(rmax, __shfl_xor(rmax, 16, 64));
        rmax = fmaxf(rmax, __shfl_xor(rmax, 32, 64));

        const float mn = fmaxf(mrow, rmax);
        const int norescale = __all(rmax <= mrow);     // exact: alpha == 1

        float csum[8];
        #pragma unroll
        for (int c = 0; c < 8; ++c) {
            #pragma unroll
            for (int r = 0; r < 4; ++r)
                Sc[c][r] = __builtin_amdgcn_exp2f(Sc[c][r] - mn);
            csum[c] = (Sc[c][0] + Sc[c][1]) + (Sc[c][2] + Sc[c][3]);
        }
        float rsum = ((csum[0] + csum[1]) + (csum[2] + csum[3]))
                   + ((csum[4] + csum[5]) + (csum[6] + csum[7]));
        rsum += __shfl_xor(rsum, 16, 64);
        rsum += __shfl_xor(rsum, 32, 64);

        if (norescale) {
            lrow += rsum;                              // mn == mrow exactly
        } else {
            const float alpha = __builtin_amdgcn_exp2f(mrow - mn);
            mrow = mn;
            lrow = lrow * alpha + rsum;
            float aO[4];
            #pragma unroll
            for (int r = 0; r < 4; ++r) aO[r] = __shfl(alpha, q4*4 + r, 64);
            #pragma unroll
            for (int c2 = 0; c2 < 4; ++c2)
                #pragma unroll
                for (int r = 0; r < 4; ++r) O[c2][r] *= aO[r];
        }

        // PV: A-frag slot (kc,q4,j) must hold P[q][s=32kc+16(j>>2)+4q4+(j&3)]
        // = lane's own Sc[c=2kc+(j>>2)][r=j&3]. Pack in-register, no LDS.
        #pragma unroll
        for (int kc = 0; kc < 4; ++kc) {
            union { u32 wd[4]; bhalf8 v; } pu;
            pu.wd[0] = pack2(Sc[2*kc    ][0], Sc[2*kc    ][1]);
            pu.wd[1] = pack2(Sc[2*kc    ][2], Sc[2*kc    ][3]);
            pu.wd[2] = pack2(Sc[2*kc + 1][0], Sc[2*kc + 1][1]);
            pu.wd[3] = pack2(Sc[2*kc + 1][2], Sc[2*kc + 1][3]);
            const bhalf8 pa = pu.v;
            #pragma unroll
            for (int c2 = 0; c2 < 4; ++c2) {
                bhalf8 bv = *(const bhalf8*)&vsT[(16*c2 + n16) * 136 + kc*32 + q4*8];
                O[c2] = __builtin_amdgcn_mfma_f32_16x16x32_bf16(pa, bv, O[c2], 0, 0, 0);
            }
        }

        kc0 = kn0; kc1 = kn1; vc0 = vn0; vc1 = vn1; vc2 = vn2; vc3 = vn3;
    }

    // Epilogue: broadcast l from row-owner lanes (q = q4*4+r lives in lane q).
    const int b = bh >> 4, h = bh & 15;
    float lb[4];
    #pragma unroll
    for (int r = 0; r < 4; ++r) lb[r] = __shfl(lrow, q4*4 + r, 64);
    #pragma unroll
    for (int r = 0; r < 4; ++r) {
        const float rl = 1.0f / lb[r];
        const int t = t0 + w*16 + q4*4 + r;
        #pragma unroll
        for (int c2 = 0; c2 < 4; ++c2)
            y[((size_t)b * T_ + t) * D_ + h * DH_ + 16*c2 + n16] = tob(O[c2][r] * rl);
    }
}

// ---------------------------------------------------------------------------
// Kernel 3: MFMA out-gemm  yb(4096,1024) @ WoT^T -> out fp32.
// 128x64 tile -> grid (16,32) = 512 blocks = 2/CU. Direct staging.
// ---------------------------------------------------------------------------
__global__ __launch_bounds__(256) void out_gemm_mfma(
    const u16* __restrict__ yb, const u16* __restrict__ WoT,
    float* __restrict__ out)
{
    __shared__ __align__(16) u16 As[128 * 72];
    __shared__ __align__(16) u16 Bs[64 * 72];
    const int tid  = threadIdx.x;
    const int lane = tid & 63;
    const int w    = tid >> 6;
    const int n16  = lane & 15;
    const int q4   = lane >> 4;
    const int wx   = w & 1;
    const int wy   = w >> 1;
    const int bm   = blockIdx.y * 128;
    const int bn   = blockIdx.x * 64;

    floatx4 acc[4][2];
    #pragma unroll
    for (int i = 0; i < 4; ++i)
        #pragma unroll
        for (int j = 0; j < 2; ++j) acc[i][j] = (floatx4)(0.f);

    for (int kt = 0; kt < D_; kt += 64) {
        #pragma unroll
        for (int p = 0; p < 4; ++p) {
            const int e = tid + p * 256;
            const int r = e >> 3, ch = (e & 7) * 8;
            *(uint4*)&As[r * 72 + ch] = *(const uint4*)(yb + (size_t)(bm + r) * D_ + kt + ch);
        }
        #pragma unroll
        for (int p = 0; p < 2; ++p) {
            const int e = tid + p * 256;
            const int r = e >> 3, ch = (e & 7) * 8;
            *(uint4*)&Bs[r * 72 + ch] = *(const uint4*)(WoT + (size_t)(bn + r) * D_ + kt + ch);
        }
        __syncthreads();
        #pragma unroll
        for (int kk = 0; kk < 2; ++kk) {
            bhalf8 a[4], b[2];
            #pragma unroll
            for (int mi = 0; mi < 4; ++mi)
                a[mi] = *(const bhalf8*)&As[(wy*64 + mi*16 + n16) * 72 + kk*32 + q4*8];
            #pragma unroll
            for (int ni = 0; ni < 2; ++ni)
                b[ni] = *(const bhalf8*)&Bs[(wx*32 + ni*16 + n16) * 72 + kk*32 + q4*8];
            #pragma unroll
            for (int mi = 0; mi < 4; ++mi)
                #pragma unroll
                for (int ni = 0; ni < 2; ++ni)
                    acc[mi][ni] = __builtin_amdgcn_mfma_f32_16x16x32_bf16(
                        a[mi], b[ni], acc[mi][ni], 0, 0, 0);
        }
        __syncthreads();
    }

    #pragma unroll
    for (int mi = 0; mi < 4; ++mi) {
        #pragma unroll
        for (int rr = 0; rr < 4; ++rr) {
            const int row = bm + wy*64 + mi*16 + q4*4 + rr;
            #pragma unroll
            for (int ni = 0; ni < 2; ++ni) {
                const int col = bn + wx*32 + ni*16 + n16;
                out[(size_t)row * D_ + col] = acc[mi][ni][rr];
            }
        }
    }
}

// ---------------------------------------------------------------------------
extern "C" void kernel_launch(void* const* d_in, const int* in_sizes, int n_in,
                              void* d_out, int out_size, void* d_ws, size_t ws_size,
                              hipStream_t stream)
{
    (void)out_size; (void)ws_size;
    const void* in_x = nullptr; const void* in_wqkv = nullptr;
    const void* in_wq = nullptr; const void* in_wk = nullptr;
    const void* in_core = nullptr; const void* in_wo = nullptr;
    for (int i = 0; i < n_in; ++i) {
        const int s = in_sizes[i];
        if      (s == BT_*D_)     { if (!in_x)    in_x    = d_in[i]; }
        else if (s == D_*3*D_)    { if (!in_wqkv) in_wqkv = d_in[i]; }
        else if (s == H_*DH_*R_)  { if (!in_wq)   in_wq   = d_in[i]; else if (!in_wk) in_wk = d_in[i]; }
        else if (s == H_*R_)      { if (!in_core) in_core = d_in[i]; }
        else if (s == D_*D_)      { if (!in_wo)   in_wo   = d_in[i]; }
    }
    if (!in_x)    in_x    = d_in[0];
    if (!in_wqkv) in_wqkv = d_in[1];
    if (!in_wq)   in_wq   = d_in[2];
    if (!in_wk)   in_wk   = d_in[3];
    if (!in_core) in_core = d_in[4];
    if (!in_wo)   in_wo   = d_in[5];

    float* out = (float*)d_out;

    char* ws    = (char*)d_ws;
    int*  flag  = (int*)(ws + WSB_FLAG);
    u16*  xb    = (u16*)(ws + WSB_XB);
    u16*  WcatT = (u16*)(ws + WSB_WCATT);
    u16*  ql    = (u16*)(ws + WSB_QL);
    u16*  kl    = (u16*)(ws + WSB_KL);
    u16*  v_t   = (u16*)(ws + WSB_VT);
    u16*  yb    = (u16*)(ws + WSB_YB);
    u16*  WoT   = (u16*)(ws + WSB_WOT);

    detect_dtype<<<1, 64, 0, stream>>>((const u32*)in_x, flag);
    convert_x<<<2048, 256, 0, stream>>>(in_x, xb, flag);
    fold_mfma<<<dim3(8, 16), 256, 0, stream>>>(in_wqkv, in_wq, in_wk, in_core, WcatT, flag);
    convert_T<<<dim3(16,16), 256, 0, stream>>>(in_wqkv, WcatT, 3*D_, 2*D_, 1024, flag); // W_v
    convert_T<<<dim3(16,16), 256, 0, stream>>>(in_wo,   WoT,   D_,   0,    0,    flag); // W_o
    gemm1_mfma<<<dim3(32, 32), 256, 0, stream>>>(xb, WcatT, ql, kl, v_t);
    attn_kernel<<<dim3(32, 32), 256, 0, stream>>>(ql, kl, v_t, yb);
    out_gemm_mfma<<<dim3(16, 32), 256, 0, stream>>>(yb, WoT, out);
}

// Round 3
// 185.450 us; speedup vs baseline: 1.0220x; 1.0220x over previous
//
#include <hip/hip_runtime.h>
#include <hip/hip_bf16.h>

// Established rounds 0-10: inputs fp32 (detector=insurance), output fp32.
// R5/R6: VALU->MFMA. R8: fold -> MFMA. R10 LESSON: reg prefetch before a
// __syncthreads is DEFEATED (barrier emits s_waitcnt vmcnt(0)). R11: direct
// stage->LDS, TLP via more blocks. R12: swapped-QK attn (S^T = mfma(K,Q)),
// lane-local softmax, exp2-domain, rescale-skip. R13: zero-LDS P path via
// sigma-permuted V slots; conflicts 7.2M->5.0M but dur 44->43: attn is NOT
// LDS-bound — it is ISSUE-bound (3060 cyc/wave-iter vs ~1000 busy; decaying
// occupancy, per-CU load imbalance 42 vs 28 iters, all-resident no-queue).
// R14 (this round):
//  attn: 512-thr blocks / 128-row q-tiles. One staging serves 8 waves
//  (staging+barriers per work HALVED), 512 blocks @ 2/CU = 16 waves/CU
//  FLAT, and qt2=(by<8)?15-by:by-8 makes co-resident pairs (b,b+256)
//  complementary -> per-CU work constant (17 iters). Per-wave work
//  unchanged (R13-verified sigma-V, reg-P, softmax).
//  gemm1: 128x128 tiles (was 128x64): 2x MFMA per staged byte, half B
//  traffic. acc[4][4], 512 blocks.
#define B_  2
#define T_  2048
#define D_  1024
#define H_  16
#define DH_ 64
#define R_  32
#define BT_ (B_*T_)          // 4096
#define BH_ (B_*H_)          // 32

typedef unsigned short u16;
typedef unsigned int   u32;
typedef __attribute__((ext_vector_type(8))) short bhalf8;   // 8 bf16 = 4 VGPRs
typedef __attribute__((ext_vector_type(4))) float floatx4;  // MFMA C/D

// Workspace layout (bytes). Total ~38 MB.
#define WSB_FLAG  0
#define WSB_XB    256                        // bf16 x     (4096,1024)  8 MB
#define WSB_WCATT (WSB_XB    + 8388608)      // bf16 WcatT (2048,1024)  4 MB
#define WSB_QL    (WSB_WCATT + 4194304)      // bf16 (B,H,T,R)          4 MB
#define WSB_KL    (WSB_QL    + 4194304)      // bf16 (B,H,T,R)          4 MB
#define WSB_VT    (WSB_KL    + 4194304)      // bf16 (B,H,DH,T)         8 MB
#define WSB_YB    (WSB_VT    + 8388608)      // bf16 y     (B,T,D)      8 MB
#define WSB_WOT   (WSB_YB    + 8388608)      // bf16 WoT   (1024,1024)  2 MB

#define NEG_ -1.0e30f

__device__ __forceinline__ float bfs(u16 s) {
    union { u32 i; float f; } w; w.i = ((u32)s) << 16; return w.f;
}
__device__ __forceinline__ u16 tob(float f) {
    __hip_bfloat16 h = __float2bfloat16(f);   // RNE
    return *(u16*)&h;
}
__device__ __forceinline__ u32 pack2(float a, float b) {
    return (u32)tob(a) | ((u32)tob(b) << 16);
}

// ---------------------------------------------------------------------------
// Kernel D: detect input dtype (1 = bf16, 0 = fp32) — insurance only.
// ---------------------------------------------------------------------------
__global__ __launch_bounds__(64) void detect_dtype(const u32* __restrict__ xw,
                                                   int* __restrict__ flag)
{
    const int tid = threadIdx.x;
    int hits = 0;
    for (int i = tid; i < 512; i += 64) {
        const u32 w = xw[i];
        const u32 h = w & 0xFFFFu;
        const u32 e = (h >> 7) & 0xFFu;
        if (h == 0u || (e >= 100u && e <= 150u)) ++hits;
    }
    #pragma unroll
    for (int off = 32; off; off >>= 1) hits += __shfl_down(hits, off, 64);
    if (tid == 0) *flag = (hits >= 300) ? 1 : 0;
}

// ---------------------------------------------------------------------------
// Kernel C: x -> xb bf16 (8 elems/thread). HBM-bound, ~24 MB traffic.
// ---------------------------------------------------------------------------
__global__ __launch_bounds__(256) void convert_x(
    const void* __restrict__ x, u16* __restrict__ xb,
    const int* __restrict__ flag)
{
    const int isbf = *flag;
    const int e = blockIdx.x * 256 + threadIdx.x;  // over 524288 (x8 elems)
    if (isbf) {
        ((uint4*)xb)[e] = ((const uint4*)x)[e];
    } else {
        float4 a0 = ((const float4*)x)[2*e];
        float4 a1 = ((const float4*)x)[2*e + 1];
        uint4 o;
        o.x = pack2(a0.x, a0.y); o.y = pack2(a0.z, a0.w);
        o.z = pack2(a1.x, a1.y); o.w = pack2(a1.z, a1.w);
        ((uint4*)xb)[e] = o;
    }
}

// ---------------------------------------------------------------------------
// Kernel 0: fold via MFMA. Per head h: Cq(32x1024) = Aq_h^T(32x64) @ Wq_h(64x1024)
// with m=r, k=dh, n=d. B operand (Wqkv slice) is k-contiguous natively.
// Scale folds 1/sqrt(32) * log2(e) so attn softmax uses native exp2.
// ---------------------------------------------------------------------------
__global__ __launch_bounds__(256) void fold_mfma(
    const void* __restrict__ Wqkv, const void* __restrict__ Wq_lsr,
    const void* __restrict__ Wk_lsr, const void* __restrict__ core,
    u16* __restrict__ WcatT, const int* __restrict__ flag)
{
    __shared__ __align__(16) u16 Bq[128 * 72];   // [n=d][k=dh]
    __shared__ __align__(16) u16 Bk[128 * 72];
    __shared__ __align__(16) u16 Aq[32 * 72];    // [m=r][k=dh]
    __shared__ __align__(16) u16 Ak[32 * 72];
    const int isbf = *flag;
    const int tid  = threadIdx.x;
    const int lane = tid & 63;
    const int w    = tid >> 6;
    const int n16  = lane & 15;
    const int q4   = lane >> 4;
    const int h    = blockIdx.y;        // 0..15
    const int d0   = blockIdx.x * 128;  // 0..896

    #pragma unroll
    for (int p = 0; p < 8; ++p) {
        const int e  = tid + p * 256;
        const int r  = e & 31, dh = e >> 5;
        float aq, ak;
        if (isbf) {
            aq = bfs(((const u16*)Wq_lsr)[(h*DH_ + dh)*R_ + r]);
            ak = bfs(((const u16*)Wk_lsr)[(h*DH_ + dh)*R_ + r]);
        } else {
            aq = ((const float*)Wq_lsr)[(h*DH_ + dh)*R_ + r];
            ak = ((const float*)Wk_lsr)[(h*DH_ + dh)*R_ + r];
        }
        Aq[r * 72 + dh] = tob(aq);
        Ak[r * 72 + dh] = tob(ak);
    }
    #pragma unroll
    for (int p = 0; p < 8; ++p) {
        const int e  = tid + p * 256;      // 0..2047
        const int n  = e >> 4, ch = e & 15;
        if (isbf) {
            uint2 wq = *(const uint2*)((const u16*)Wqkv + (size_t)(d0+n)*(3*D_) + h*DH_ + ch*4);
            uint2 wk = *(const uint2*)((const u16*)Wqkv + (size_t)(d0+n)*(3*D_) + D_ + h*DH_ + ch*4);
            *(uint2*)&Bq[n * 72 + ch*4] = wq;
            *(uint2*)&Bk[n * 72 + ch*4] = wk;
        } else {
            float4 fq = *(const float4*)((const float*)Wqkv + (size_t)(d0+n)*(3*D_) + h*DH_ + ch*4);
            float4 fk = *(const float4*)((const float*)Wqkv + (size_t)(d0+n)*(3*D_) + D_ + h*DH_ + ch*4);
            uint2 oq, ok;
            oq.x = pack2(fq.x, fq.y); oq.y = pack2(fq.z, fq.w);
            ok.x = pack2(fk.x, fk.y); ok.y = pack2(fk.z, fk.w);
            *(uint2*)&Bq[n * 72 + ch*4] = oq;
            *(uint2*)&Bk[n * 72 + ch*4] = ok;
        }
    }
    __syncthreads();

    floatx4 accq[2][2], acck[2][2];
    #pragma unroll
    for (int mi = 0; mi < 2; ++mi)
        #pragma unroll
        for (int ni = 0; ni < 2; ++ni) { accq[mi][ni] = (floatx4)(0.f); acck[mi][ni] = (floatx4)(0.f); }

    #pragma unroll
    for (int kk = 0; kk < 2; ++kk) {
        bhalf8 aqf[2], akf[2], bqf[2], bkf[2];
        #pragma unroll
        for (int mi = 0; mi < 2; ++mi) {
            aqf[mi] = *(const bhalf8*)&Aq[(mi*16 + n16) * 72 + kk*32 + q4*8];
            akf[mi] = *(const bhalf8*)&Ak[(mi*16 + n16) * 72 + kk*32 + q4*8];
        }
        #pragma unroll
        for (int ni = 0; ni < 2; ++ni) {
            bqf[ni] = *(const bhalf8*)&Bq[(w*32 + ni*16 + n16) * 72 + kk*32 + q4*8];
            bkf[ni] = *(const bhalf8*)&Bk[(w*32 + ni*16 + n16) * 72 + kk*32 + q4*8];
        }
        #pragma unroll
        for (int mi = 0; mi < 2; ++mi)
            #pragma unroll
            for (int ni = 0; ni < 2; ++ni) {
                accq[mi][ni] = __builtin_amdgcn_mfma_f32_16x16x32_bf16(aqf[mi], bqf[ni], accq[mi][ni], 0, 0, 0);
                acck[mi][ni] = __builtin_amdgcn_mfma_f32_16x16x32_bf16(akf[mi], bkf[ni], acck[mi][ni], 0, 0, 0);
            }
    }

    // 1/sqrt(32) * log2(e): softmax done in exp2 domain (native v_exp_f32).
    const float scale = (float)(0.17677669529663687 * 1.4426950408889634);
    #pragma unroll
    for (int mi = 0; mi < 2; ++mi) {
        #pragma unroll
        for (int rr = 0; rr < 4; ++rr) {
            const int r = mi*16 + q4*4 + rr;
            const float cc = (isbf ? bfs(((const u16*)core)[h*R_ + r])
                                   : ((const float*)core)[h*R_ + r]) * scale;
            #pragma unroll
            for (int ni = 0; ni < 2; ++ni) {
                const int d = d0 + w*32 + ni*16 + n16;
                WcatT[(size_t)(h*R_ + r) * D_ + d]       = tob(accq[mi][ni][rr] * cc);
                WcatT[(size_t)(512 + h*R_ + r) * D_ + d] = tob(acck[mi][ni][rr]);
            }
        }
    }
}

// ---------------------------------------------------------------------------
// Kernel T: generic transposing convert (fp32/bf16 -> bf16), 64x64 tiles.
// ---------------------------------------------------------------------------
__global__ __launch_bounds__(256) void convert_T(
    const void* __restrict__ src, u16* __restrict__ dst,
    int srcStride, int srcColOff, int dstRowOff, const int* __restrict__ flag)
{
    __shared__ __align__(16) u16 tile[64 * 72];
    const int isbf = *flag;
    const int tid = threadIdx.x;
    const int j0  = blockIdx.x * 64;
    const int i0  = blockIdx.y * 64;
    #pragma unroll
    for (int p = 0; p < 2; ++p) {
        const int e = tid + p * 256;
        const int r = e >> 3, ch = e & 7;
        if (isbf) {
            uint4 w = *(const uint4*)((const u16*)src + (size_t)(i0 + r) * srcStride + srcColOff + j0 + ch*8);
            *(uint4*)&tile[r * 72 + ch*8] = w;
        } else {
            const float* s = (const float*)src + (size_t)(i0 + r) * srcStride + srcColOff + j0 + ch*8;
            float4 a0 = *(const float4*)s;
            float4 a1 = *(const float4*)(s + 4);
            uint4 o;
            o.x = pack2(a0.x, a0.y); o.y = pack2(a0.z, a0.w);
            o.z = pack2(a1.x, a1.y); o.w = pack2(a1.z, a1.w);
            *(uint4*)&tile[r * 72 + ch*8] = o;
        }
    }
    __syncthreads();
    #pragma unroll
    for (int p = 0; p < 2; ++p) {
        const int e = tid + p * 256;
        const int c = e >> 3, ch = e & 7;
        u16 tmp[8];
        #pragma unroll
        for (int j = 0; j < 8; ++j) tmp[j] = tile[(ch*8 + j) * 72 + c];
        *(uint4*)(dst + (size_t)(dstRowOff + j0 + c) * D_ + i0 + ch*8) = *(uint4*)tmp;
    }
}

// ---------------------------------------------------------------------------
// Kernel 1 (R14): MFMA gemm1  xb(4096,1024) @ WcatT^T -> ql/kl + v_t.
// 128x128 tile, BK=64, 4 waves each 64x64 (acc[4][4]). Grid (16,32) = 512
// blocks = 2/CU. 2x MFMA per staged byte vs 128x64; B traffic halved.
// ---------------------------------------------------------------------------
__global__ __launch_bounds__(256, 2) void gemm1_mfma(
    const u16* __restrict__ xb, const u16* __restrict__ WcatT,
    u16* __restrict__ ql, u16* __restrict__ kl, u16* __restrict__ v_t)
{
    __shared__ __align__(16) u16 As[128 * 72];   // 18432 B
    __shared__ __align__(16) u16 Bs[128 * 72];   // 18432 B
    const int tid  = threadIdx.x;
    const int lane = tid & 63;
    const int w    = tid >> 6;
    const int n16  = lane & 15;
    const int q4   = lane >> 4;
    const int wx   = w & 1;          // n-half (64 cols)
    const int wy   = w >> 1;         // m-half (64 rows)
    const int bm   = blockIdx.y * 128;
    const int bn   = blockIdx.x * 128;

    floatx4 acc[4][4];
    #pragma unroll
    for (int i = 0; i < 4; ++i)
        #pragma unroll
        for (int j = 0; j < 4; ++j) acc[i][j] = (floatx4)(0.f);

    for (int kt = 0; kt < D_; kt += 64) {
        #pragma unroll
        for (int p = 0; p < 4; ++p) {
            const int e = tid + p * 256;       // 0..1023
            const int r = e >> 3, ch = (e & 7) * 8;
            *(uint4*)&As[r * 72 + ch] = *(const uint4*)(xb    + (size_t)(bm + r) * D_ + kt + ch);
            *(uint4*)&Bs[r * 72 + ch] = *(const uint4*)(WcatT + (size_t)(bn + r) * D_ + kt + ch);
        }
        __syncthreads();
        #pragma unroll
        for (int kk = 0; kk < 2; ++kk) {
            bhalf8 a[4], b[4];
            #pragma unroll
            for (int mi = 0; mi < 4; ++mi)
                a[mi] = *(const bhalf8*)&As[(wy*64 + mi*16 + n16) * 72 + kk*32 + q4*8];
            #pragma unroll
            for (int ni = 0; ni < 4; ++ni)
                b[ni] = *(const bhalf8*)&Bs[(wx*64 + ni*16 + n16) * 72 + kk*32 + q4*8];
            #pragma unroll
            for (int mi = 0; mi < 4; ++mi)
                #pragma unroll
                for (int ni = 0; ni < 4; ++ni)
                    acc[mi][ni] = __builtin_amdgcn_mfma_f32_16x16x32_bf16(
                        a[mi], b[ni], acc[mi][ni], 0, 0, 0);
        }
        __syncthreads();
    }

    if (bn < 1024) {
        #pragma unroll
        for (int mi = 0; mi < 4; ++mi) {
            #pragma unroll
            for (int rr = 0; rr < 4; ++rr) {
                const int row = bm + wy*64 + mi*16 + q4*4 + rr;
                const int b   = row >> 11;
                const int t   = row & (T_ - 1);
                #pragma unroll
                for (int ni = 0; ni < 4; ++ni) {
                    const int col = bn + wx*64 + ni*16 + n16;
                    const u16 val = tob(acc[mi][ni][rr]);
                    if (col < 512) {
                        const int h = col >> 5, r = col & 31;
                        ql[((size_t)(b*H_ + h)*T_ + t)*R_ + r] = val;
                    } else {
                        const int c = col - 512; const int h = c >> 5, r = c & 31;
                        kl[((size_t)(b*H_ + h)*T_ + t)*R_ + r] = val;
                    }
                }
            }
        }
    } else {
        // v: write v_t (B,H,DH,T) directly — 4 consecutive t pack into 8B
        #pragma unroll
        for (int mi = 0; mi < 4; ++mi) {
            const int row0 = bm + wy*64 + mi*16 + q4*4;
            const int b = row0 >> 11;
            const int t = row0 & (T_ - 1);
            #pragma unroll
            for (int ni = 0; ni < 4; ++ni) {
                const int c = bn - 1024 + wx*64 + ni*16 + n16;
                const int h = c >> 6, dh = c & 63;
                uint2 o;
                o.x = pack2(acc[mi][ni][0], acc[mi][ni][1]);
                o.y = pack2(acc[mi][ni][2], acc[mi][ni][3]);
                *(uint2*)(v_t + ((size_t)(b*H_ + h) * DH_ + dh) * T_ + t) = o;
            }
        }
    }
}

// ---------------------------------------------------------------------------
// softmax update for one 16-row q-group (R13-verified logic, refactored).
// ---------------------------------------------------------------------------
__device__ __forceinline__ void softmax_update(
    floatx4 (&Sc)[8], float &mrow, float &lrow, floatx4 (&O)[4], int q4)
{
    float cmax[8];
    #pragma unroll
    for (int c = 0; c < 8; ++c)
        cmax[c] = fmaxf(fmaxf(Sc[c][0], Sc[c][1]), fmaxf(Sc[c][2], Sc[c][3]));
    float rmax = fmaxf(fmaxf(fmaxf(cmax[0], cmax[1]), fmaxf(cmax[2], cmax[3])),
                       fmaxf(fmaxf(cmax[4], cmax[5]), fmaxf(cmax[6], cmax[7])));
    rmax = fmaxf(rmax, __shfl_xor(rmax, 16, 64));
    rmax = fmaxf(rmax, __shfl_xor(rmax, 32, 64));

    const float mn = fmaxf(mrow, rmax);
    const int norescale = __all(rmax <= mrow);     // exact: alpha == 1

    float csum[8];
    #pragma unroll
    for (int c = 0; c < 8; ++c) {
        #pragma unroll
        for (int r = 0; r < 4; ++r)
            Sc[c][r] = __builtin_amdgcn_exp2f(Sc[c][r] - mn);
        csum[c] = (Sc[c][0] + Sc[c][1]) + (Sc[c][2] + Sc[c][3]);
    }
    float rsum = ((csum[0] + csum[1]) + (csum[2] + csum[3]))
               + ((csum[4] + csum[5]) + (csum[6] + csum[7]));
    rsum += __shfl_xor(rsum, 16, 64);
    rsum += __shfl_xor(rsum, 32, 64);

    if (norescale) {
        lrow += rsum;                              // mn == mrow exactly
    } else {
        const float alpha = __builtin_amdgcn_exp2f(mrow - mn);
        mrow = mn;
        lrow = lrow * alpha + rsum;
        float aO[4];
        #pragma unroll
        for (int r = 0; r < 4; ++r) aO[r] = __shfl(alpha, q4*4 + r, 64);
        #pragma unroll
        for (int c2 = 0; c2 < 4; ++c2)
            #pragma unroll
            for (int r = 0; r < 4; ++r) O[c2][r] *= aO[r];
    }
}

// ---------------------------------------------------------------------------
// Kernel 2 (R14): swapped-QK flash attention, 512-thr blocks, 128-row
// q-tiles. 8 waves x 16 q-rows; one K/V staging serves all 8 waves
// (staging + barriers per unit work halved vs R13). Zero-LDS P path via
// sigma-permuted vsT (R13). Uniform per-CU work: qt2=(by<8)?15-by:by-8
// makes co-resident pair (b, b+256) complementary (17 iters const).
// ---------------------------------------------------------------------------
__global__ __launch_bounds__(512, 4) void attn_kernel(
    const u16* __restrict__ ql, const u16* __restrict__ kl,
    const u16* __restrict__ v_t, u16* __restrict__ y)
{
    __shared__ __align__(16) u16 kls[128 * 40];      // 10240 B
    __shared__ __align__(16) u16 vsT[64 * 136];      // 17408 B, sigma-permuted

    const int tid  = threadIdx.x;
    const int lane = tid & 63;
    const int w    = tid >> 6;               // 0..7
    const int n16  = lane & 15;
    const int q4   = lane >> 4;
    const int bh   = blockIdx.x;
    const int by   = blockIdx.y;             // 0..15
    const int qt2  = (by < 8) ? (15 - by) : (by - 8);  // complementary pairs
    const int t0   = qt2 * 128;
    const int nt   = qt2 + 1;                // # of 128-wide s-tiles

    // Q fragment = B-operand of swapped QK^T; loads directly in frag layout.
    const u16* qlb = ql + (size_t)bh * T_ * R_;
    const bhalf8 aq = *(const bhalf8*)(qlb + (size_t)(t0 + w*16 + n16) * R_ + q4*8);

    const u16* klb = kl  + (size_t)bh * T_ * R_;
    const u16* vtb = v_t + (size_t)bh * DH_ * T_;
    const int rk = tid >> 2, ck = (tid & 3) * 8;   // kls: 128 rows x 32, 1 b128/thread
    const int dv = tid >> 4;                       // vsT rows dv, dv+32
    const int m  = tid & 15;
    const int cv = m * 8;
    // sigma staging base: 8 consecutive s (=8m+i) -> two uint2 at pb, pb+8.
    const int pb = ((m & 1) << 4) | (((m >> 1) & 1) << 2) | ((m >> 2) << 5);

    uint4 kc0 = *(const uint4*)(klb + (size_t)(rk     ) * R_ + ck);
    uint4 vc0 = *(const uint4*)(vtb + (size_t)(dv     ) * T_ + cv);
    uint4 vc1 = *(const uint4*)(vtb + (size_t)(dv + 32) * T_ + cv);
    uint4 kn0 = kc0, vn0 = vc0, vn1 = vc1;

    float mrow = NEG_, lrow = 0.f;           // one q-row per lane
    floatx4 O[4];
    #pragma unroll
    for (int c = 0; c < 4; ++c) O[c] = (floatx4)(0.f);

    for (int it = 0; it < nt; ++it) {
        const int s0 = it * 128;
        __syncthreads();
        *(uint4*)&kls[rk * 40 + ck] = kc0;
        {
            uint2 t;
            t.x = vc0.x; t.y = vc0.y; *(uint2*)&vsT[(dv     ) * 136 + pb    ] = t;
            t.x = vc0.z; t.y = vc0.w; *(uint2*)&vsT[(dv     ) * 136 + pb + 8] = t;
            t.x = vc1.x; t.y = vc1.y; *(uint2*)&vsT[(dv + 32) * 136 + pb    ] = t;
            t.x = vc1.z; t.y = vc1.w; *(uint2*)&vsT[(dv + 32) * 136 + pb + 8] = t;
        }
        if (it + 1 < nt) {
            const int s1 = s0 + 128;
            kn0 = *(const uint4*)(klb + (size_t)(s1 + rk) * R_ + ck);
            vn0 = *(const uint4*)(vtb + (size_t)(dv     ) * T_ + s1 + cv);
            vn1 = *(const uint4*)(vtb + (size_t)(dv + 32) * T_ + s1 + cv);
        }
        __syncthreads();

        // S^T: A = K-frag (m=s), B = Q-frag (n=q). Lane: q=n16, s=16c+4q4+r.
        floatx4 Sc[8];
        #pragma unroll
        for (int c = 0; c < 8; ++c) {
            bhalf8 ak = *(const bhalf8*)&kls[(16*c + n16) * 40 + q4*8];
            Sc[c] = __builtin_amdgcn_mfma_f32_16x16x32_bf16(ak, aq, (floatx4)(0.f), 0, 0, 0);
        }

        if (it == nt - 1) {
            const int tq = w*16 + n16;                 // local q row (0..127)
            #pragma unroll
            for (int c = 0; c < 8; ++c) {
                const int sb = 16*c + 4*q4;            // local s base (s0==t0)
                #pragma unroll
                for (int r = 0; r < 4; ++r)
                    if (sb + r > tq) Sc[c][r] = NEG_;
            }
        }

        softmax_update(Sc, mrow, lrow, O, q4);

        // PV: A-frag slot (kc,q4,j) must hold P[q][s=32kc+16(j>>2)+4q4+(j&3)]
        // = lane's own Sc[c=2kc+(j>>2)][r=j&3]. Pack in-register, no LDS.
        #pragma unroll
        for (int kc = 0; kc < 4; ++kc) {
            union { u32 wd[4]; bhalf8 v; } pu;
            pu.wd[0] = pack2(Sc[2*kc    ][0], Sc[2*kc    ][1]);
            pu.wd[1] = pack2(Sc[2*kc    ][2], Sc[2*kc    ][3]);
            pu.wd[2] = pack2(Sc[2*kc + 1][0], Sc[2*kc + 1][1]);
            pu.wd[3] = pack2(Sc[2*kc + 1][2], Sc[2*kc + 1][3]);
            const bhalf8 pa = pu.v;
            #pragma unroll
            for (int c2 = 0; c2 < 4; ++c2) {
                bhalf8 bv = *(const bhalf8*)&vsT[(16*c2 + n16) * 136 + kc*32 + q4*8];
                O[c2] = __builtin_amdgcn_mfma_f32_16x16x32_bf16(pa, bv, O[c2], 0, 0, 0);
            }
        }

        kc0 = kn0; vc0 = vn0; vc1 = vn1;
    }

    // Epilogue: broadcast l from row-owner lanes (q = q4*4+r lives in lane q).
    const int b = bh >> 4, h = bh & 15;
    float lb[4];
    #pragma unroll
    for (int r = 0; r < 4; ++r) lb[r] = __shfl(lrow, q4*4 + r, 64);
    #pragma unroll
    for (int r = 0; r < 4; ++r) {
        const float rl = 1.0f / lb[r];
        const int t = t0 + w*16 + q4*4 + r;
        #pragma unroll
        for (int c2 = 0; c2 < 4; ++c2)
            y[((size_t)b * T_ + t) * D_ + h * DH_ + 16*c2 + n16] = tob(O[c2][r] * rl);
    }
}

// ---------------------------------------------------------------------------
// Kernel 3: MFMA out-gemm  yb(4096,1024) @ WoT^T -> out fp32.
// 128x64 tile -> grid (16,32) = 512 blocks = 2/CU. Direct staging.
// ---------------------------------------------------------------------------
__global__ __launch_bounds__(256) void out_gemm_mfma(
    const u16* __restrict__ yb, const u16* __restrict__ WoT,
    float* __restrict__ out)
{
    __shared__ __align__(16) u16 As[128 * 72];
    __shared__ __align__(16) u16 Bs[64 * 72];
    const int tid  = threadIdx.x;
    const int lane = tid & 63;
    const int w    = tid >> 6;
    const int n16  = lane & 15;
    const int q4   = lane >> 4;
    const int wx   = w & 1;
    const int wy   = w >> 1;
    const int bm   = blockIdx.y * 128;
    const int bn   = blockIdx.x * 64;

    floatx4 acc[4][2];
    #pragma unroll
    for (int i = 0; i < 4; ++i)
        #pragma unroll
        for (int j = 0; j < 2; ++j) acc[i][j] = (floatx4)(0.f);

    for (int kt = 0; kt < D_; kt += 64) {
        #pragma unroll
        for (int p = 0; p < 4; ++p) {
            const int e = tid + p * 256;
            const int r = e >> 3, ch = (e & 7) * 8;
            *(uint4*)&As[r * 72 + ch] = *(const uint4*)(yb + (size_t)(bm + r) * D_ + kt + ch);
        }
        #pragma unroll
        for (int p = 0; p < 2; ++p) {
            const int e = tid + p * 256;
            const int r = e >> 3, ch = (e & 7) * 8;
            *(uint4*)&Bs[r * 72 + ch] = *(const uint4*)(WoT + (size_t)(bn + r) * D_ + kt + ch);
        }
        __syncthreads();
        #pragma unroll
        for (int kk = 0; kk < 2; ++kk) {
            bhalf8 a[4], b[2];
            #pragma unroll
            for (int mi = 0; mi < 4; ++mi)
                a[mi] = *(const bhalf8*)&As[(wy*64 + mi*16 + n16) * 72 + kk*32 + q4*8];
            #pragma unroll
            for (int ni = 0; ni < 2; ++ni)
                b[ni] = *(const bhalf8*)&Bs[(wx*32 + ni*16 + n16) * 72 + kk*32 + q4*8];
            #pragma unroll
            for (int mi = 0; mi < 4; ++mi)
                #pragma unroll
                for (int ni = 0; ni < 2; ++ni)
                    acc[mi][ni] = __builtin_amdgcn_mfma_f32_16x16x32_bf16(
                        a[mi], b[ni], acc[mi][ni], 0, 0, 0);
        }
        __syncthreads();
    }

    #pragma unroll
    for (int mi = 0; mi < 4; ++mi) {
        #pragma unroll
        for (int rr = 0; rr < 4; ++rr) {
            const int row = bm + wy*64 + mi*16 + q4*4 + rr;
            #pragma unroll
            for (int ni = 0; ni < 2; ++ni) {
                const int col = bn + wx*32 + ni*16 + n16;
                out[(size_t)row * D_ + col] = acc[mi][ni][rr];
            }
        }
    }
}

// ---------------------------------------------------------------------------
extern "C" void kernel_launch(void* const* d_in, const int* in_sizes, int n_in,
                              void* d_out, int out_size, void* d_ws, size_t ws_size,
                              hipStream_t stream)
{
    (void)out_size; (void)ws_size;
    const void* in_x = nullptr; const void* in_wqkv = nullptr;
    const void* in_wq = nullptr; const void* in_wk = nullptr;
    const void* in_core = nullptr; const void* in_wo = nullptr;
    for (int i = 0; i < n_in; ++i) {
        const int s = in_sizes[i];
        if      (s == BT_*D_)     { if (!in_x)    in_x    = d_in[i]; }
        else if (s == D_*3*D_)    { if (!in_wqkv) in_wqkv = d_in[i]; }
        else if (s == H_*DH_*R_)  { if (!in_wq)   in_wq   = d_in[i]; else if (!in_wk) in_wk = d_in[i]; }
        else if (s == H_*R_)      { if (!in_core) in_core = d_in[i]; }
        else if (s == D_*D_)      { if (!in_wo)   in_wo   = d_in[i]; }
    }
    if (!in_x)    in_x    = d_in[0];
    if (!in_wqkv) in_wqkv = d_in[1];
    if (!in_wq)   in_wq   = d_in[2];
    if (!in_wk)   in_wk   = d_in[3];
    if (!in_core) in_core = d_in[4];
    if (!in_wo)   in_wo   = d_in[5];

    float* out = (float*)d_out;

    char* ws    = (char*)d_ws;
    int*  flag  = (int*)(ws + WSB_FLAG);
    u16*  xb    = (u16*)(ws + WSB_XB);
    u16*  WcatT = (u16*)(ws + WSB_WCATT);
    u16*  ql    = (u16*)(ws + WSB_QL);
    u16*  kl    = (u16*)(ws + WSB_KL);
    u16*  v_t   = (u16*)(ws + WSB_VT);
    u16*  yb    = (u16*)(ws + WSB_YB);
    u16*  WoT   = (u16*)(ws + WSB_WOT);

    detect_dtype<<<1, 64, 0, stream>>>((const u32*)in_x, flag);
    convert_x<<<2048, 256, 0, stream>>>(in_x, xb, flag);
    fold_mfma<<<dim3(8, 16), 256, 0, stream>>>(in_wqkv, in_wq, in_wk, in_core, WcatT, flag);
    convert_T<<<dim3(16,16), 256, 0, stream>>>(in_wqkv, WcatT, 3*D_, 2*D_, 1024, flag); // W_v
    convert_T<<<dim3(16,16), 256, 0, stream>>>(in_wo,   WoT,   D_,   0,    0,    flag); // W_o
    gemm1_mfma<<<dim3(16, 32), 256, 0, stream>>>(xb, WcatT, ql, kl, v_t);
    attn_kernel<<<dim3(32, 16), 512, 0, stream>>>(ql, kl, v_t, yb);
    out_gemm_mfma<<<dim3(16, 32), 256, 0, stream>>>(yb, WoT, out);
}

// Round 4
// 185.035 us; speedup vs baseline: 1.0243x; 1.0022x over previous
//
#include <hip/hip_runtime.h>
#include <hip/hip_bf16.h>

// Established rounds 0-10: inputs fp32 (detector=insurance), output fp32.
// R5/R6: VALU->MFMA. R8: fold -> MFMA. R10 LESSON: reg prefetch before a
// __syncthreads is DEFEATED (barrier emits s_waitcnt vmcnt(0)). R11: direct
// stage->LDS, TLP via more blocks. R12: swapped-QK attn (S^T = mfma(K,Q)),
// lane-local softmax, exp2-domain, rescale-skip. R13: zero-LDS P path via
// sigma-permuted V slots; proved attn is issue-bound, not LDS-bound.
// R14: attn 512-thr/128-row q-tiles, complementary pairing (flat per-CU
// work); gemm1 128x128. attn+gemm1 now both under the 43us harness fills.
// R15 (this round): GEMM staging via __builtin_amdgcn_global_load_lds
// width=16 (Common-mistake #1: compiler never auto-emits it; +67% on this
// exact 128^2/BK=64/2-barrier structure per m193 A/B). Requires LINEAR
// (unpadded) LDS dest -> fragment ds_reads become 16-way bank-conflicted,
// which is benign at 2-phase (m97: 874 TF with 1.7e7 conflicts; critical
// path is stage+barrier per m233). gemm1 + out_gemm converted; attn fixed.
#define B_  2
#define T_  2048
#define D_  1024
#define H_  16
#define DH_ 64
#define R_  32
#define BT_ (B_*T_)          // 4096
#define BH_ (B_*H_)          // 32

typedef unsigned short u16;
typedef unsigned int   u32;
typedef __attribute__((ext_vector_type(8))) short bhalf8;   // 8 bf16 = 4 VGPRs
typedef __attribute__((ext_vector_type(4))) float floatx4;  // MFMA C/D

// Workspace layout (bytes). Total ~38 MB.
#define WSB_FLAG  0
#define WSB_XB    256                        // bf16 x     (4096,1024)  8 MB
#define WSB_WCATT (WSB_XB    + 8388608)      // bf16 WcatT (2048,1024)  4 MB
#define WSB_QL    (WSB_WCATT + 4194304)      // bf16 (B,H,T,R)          4 MB
#define WSB_KL    (WSB_QL    + 4194304)      // bf16 (B,H,T,R)          4 MB
#define WSB_VT    (WSB_KL    + 4194304)      // bf16 (B,H,DH,T)         8 MB
#define WSB_YB    (WSB_VT    + 8388608)      // bf16 y     (B,T,D)      8 MB
#define WSB_WOT   (WSB_YB    + 8388608)      // bf16 WoT   (1024,1024)  2 MB

#define NEG_ -1.0e30f

__device__ __forceinline__ float bfs(u16 s) {
    union { u32 i; float f; } w; w.i = ((u32)s) << 16; return w.f;
}
__device__ __forceinline__ u16 tob(float f) {
    __hip_bfloat16 h = __float2bfloat16(f);   // RNE
    return *(u16*)&h;
}
__device__ __forceinline__ u32 pack2(float a, float b) {
    return (u32)tob(a) | ((u32)tob(b) << 16);
}
// Direct global->LDS staging, 16B/lane. LDS base must be wave-uniform;
// HW writes base + lane*16. Global address is per-lane.
__device__ __forceinline__ void gload16(const u16* g, u16* l) {
    __builtin_amdgcn_global_load_lds(
        (const __attribute__((address_space(1))) void*)g,
        (__attribute__((address_space(3))) void*)l, 16, 0, 0);
}

// ---------------------------------------------------------------------------
// Kernel D: detect input dtype (1 = bf16, 0 = fp32) — insurance only.
// ---------------------------------------------------------------------------
__global__ __launch_bounds__(64) void detect_dtype(const u32* __restrict__ xw,
                                                   int* __restrict__ flag)
{
    const int tid = threadIdx.x;
    int hits = 0;
    for (int i = tid; i < 512; i += 64) {
        const u32 w = xw[i];
        const u32 h = w & 0xFFFFu;
        const u32 e = (h >> 7) & 0xFFu;
        if (h == 0u || (e >= 100u && e <= 150u)) ++hits;
    }
    #pragma unroll
    for (int off = 32; off; off >>= 1) hits += __shfl_down(hits, off, 64);
    if (tid == 0) *flag = (hits >= 300) ? 1 : 0;
}

// ---------------------------------------------------------------------------
// Kernel C: x -> xb bf16 (8 elems/thread). HBM-bound, ~24 MB traffic.
// ---------------------------------------------------------------------------
__global__ __launch_bounds__(256) void convert_x(
    const void* __restrict__ x, u16* __restrict__ xb,
    const int* __restrict__ flag)
{
    const int isbf = *flag;
    const int e = blockIdx.x * 256 + threadIdx.x;  // over 524288 (x8 elems)
    if (isbf) {
        ((uint4*)xb)[e] = ((const uint4*)x)[e];
    } else {
        float4 a0 = ((const float4*)x)[2*e];
        float4 a1 = ((const float4*)x)[2*e + 1];
        uint4 o;
        o.x = pack2(a0.x, a0.y); o.y = pack2(a0.z, a0.w);
        o.z = pack2(a1.x, a1.y); o.w = pack2(a1.z, a1.w);
        ((uint4*)xb)[e] = o;
    }
}

// ---------------------------------------------------------------------------
// Kernel 0: fold via MFMA. Per head h: Cq(32x1024) = Aq_h^T(32x64) @ Wq_h(64x1024)
// with m=r, k=dh, n=d. B operand (Wqkv slice) is k-contiguous natively.
// Scale folds 1/sqrt(32) * log2(e) so attn softmax uses native exp2.
// ---------------------------------------------------------------------------
__global__ __launch_bounds__(256) void fold_mfma(
    const void* __restrict__ Wqkv, const void* __restrict__ Wq_lsr,
    const void* __restrict__ Wk_lsr, const void* __restrict__ core,
    u16* __restrict__ WcatT, const int* __restrict__ flag)
{
    __shared__ __align__(16) u16 Bq[128 * 72];   // [n=d][k=dh]
    __shared__ __align__(16) u16 Bk[128 * 72];
    __shared__ __align__(16) u16 Aq[32 * 72];    // [m=r][k=dh]
    __shared__ __align__(16) u16 Ak[32 * 72];
    const int isbf = *flag;
    const int tid  = threadIdx.x;
    const int lane = tid & 63;
    const int w    = tid >> 6;
    const int n16  = lane & 15;
    const int q4   = lane >> 4;
    const int h    = blockIdx.y;        // 0..15
    const int d0   = blockIdx.x * 128;  // 0..896

    #pragma unroll
    for (int p = 0; p < 8; ++p) {
        const int e  = tid + p * 256;
        const int r  = e & 31, dh = e >> 5;
        float aq, ak;
        if (isbf) {
            aq = bfs(((const u16*)Wq_lsr)[(h*DH_ + dh)*R_ + r]);
            ak = bfs(((const u16*)Wk_lsr)[(h*DH_ + dh)*R_ + r]);
        } else {
            aq = ((const float*)Wq_lsr)[(h*DH_ + dh)*R_ + r];
            ak = ((const float*)Wk_lsr)[(h*DH_ + dh)*R_ + r];
        }
        Aq[r * 72 + dh] = tob(aq);
        Ak[r * 72 + dh] = tob(ak);
    }
    #pragma unroll
    for (int p = 0; p < 8; ++p) {
        const int e  = tid + p * 256;      // 0..2047
        const int n  = e >> 4, ch = e & 15;
        if (isbf) {
            uint2 wq = *(const uint2*)((const u16*)Wqkv + (size_t)(d0+n)*(3*D_) + h*DH_ + ch*4);
            uint2 wk = *(const uint2*)((const u16*)Wqkv + (size_t)(d0+n)*(3*D_) + D_ + h*DH_ + ch*4);
            *(uint2*)&Bq[n * 72 + ch*4] = wq;
            *(uint2*)&Bk[n * 72 + ch*4] = wk;
        } else {
            float4 fq = *(const float4*)((const float*)Wqkv + (size_t)(d0+n)*(3*D_) + h*DH_ + ch*4);
            float4 fk = *(const float4*)((const float*)Wqkv + (size_t)(d0+n)*(3*D_) + D_ + h*DH_ + ch*4);
            uint2 oq, ok;
            oq.x = pack2(fq.x, fq.y); oq.y = pack2(fq.z, fq.w);
            ok.x = pack2(fk.x, fk.y); ok.y = pack2(fk.z, fk.w);
            *(uint2*)&Bq[n * 72 + ch*4] = oq;
            *(uint2*)&Bk[n * 72 + ch*4] = ok;
        }
    }
    __syncthreads();

    floatx4 accq[2][2], acck[2][2];
    #pragma unroll
    for (int mi = 0; mi < 2; ++mi)
        #pragma unroll
        for (int ni = 0; ni < 2; ++ni) { accq[mi][ni] = (floatx4)(0.f); acck[mi][ni] = (floatx4)(0.f); }

    #pragma unroll
    for (int kk = 0; kk < 2; ++kk) {
        bhalf8 aqf[2], akf[2], bqf[2], bkf[2];
        #pragma unroll
        for (int mi = 0; mi < 2; ++mi) {
            aqf[mi] = *(const bhalf8*)&Aq[(mi*16 + n16) * 72 + kk*32 + q4*8];
            akf[mi] = *(const bhalf8*)&Ak[(mi*16 + n16) * 72 + kk*32 + q4*8];
        }
        #pragma unroll
        for (int ni = 0; ni < 2; ++ni) {
            bqf[ni] = *(const bhalf8*)&Bq[(w*32 + ni*16 + n16) * 72 + kk*32 + q4*8];
            bkf[ni] = *(const bhalf8*)&Bk[(w*32 + ni*16 + n16) * 72 + kk*32 + q4*8];
        }
        #pragma unroll
        for (int mi = 0; mi < 2; ++mi)
            #pragma unroll
            for (int ni = 0; ni < 2; ++ni) {
                accq[mi][ni] = __builtin_amdgcn_mfma_f32_16x16x32_bf16(aqf[mi], bqf[ni], accq[mi][ni], 0, 0, 0);
                acck[mi][ni] = __builtin_amdgcn_mfma_f32_16x16x32_bf16(akf[mi], bkf[ni], acck[mi][ni], 0, 0, 0);
            }
    }

    // 1/sqrt(32) * log2(e): softmax done in exp2 domain (native v_exp_f32).
    const float scale = (float)(0.17677669529663687 * 1.4426950408889634);
    #pragma unroll
    for (int mi = 0; mi < 2; ++mi) {
        #pragma unroll
        for (int rr = 0; rr < 4; ++rr) {
            const int r = mi*16 + q4*4 + rr;
            const float cc = (isbf ? bfs(((const u16*)core)[h*R_ + r])
                                   : ((const float*)core)[h*R_ + r]) * scale;
            #pragma unroll
            for (int ni = 0; ni < 2; ++ni) {
                const int d = d0 + w*32 + ni*16 + n16;
                WcatT[(size_t)(h*R_ + r) * D_ + d]       = tob(accq[mi][ni][rr] * cc);
                WcatT[(size_t)(512 + h*R_ + r) * D_ + d] = tob(acck[mi][ni][rr]);
            }
        }
    }
}

// ---------------------------------------------------------------------------
// Kernel T: generic transposing convert (fp32/bf16 -> bf16), 64x64 tiles.
// ---------------------------------------------------------------------------
__global__ __launch_bounds__(256) void convert_T(
    const void* __restrict__ src, u16* __restrict__ dst,
    int srcStride, int srcColOff, int dstRowOff, const int* __restrict__ flag)
{
    __shared__ __align__(16) u16 tile[64 * 72];
    const int isbf = *flag;
    const int tid = threadIdx.x;
    const int j0  = blockIdx.x * 64;
    const int i0  = blockIdx.y * 64;
    #pragma unroll
    for (int p = 0; p < 2; ++p) {
        const int e = tid + p * 256;
        const int r = e >> 3, ch = e & 7;
        if (isbf) {
            uint4 w = *(const uint4*)((const u16*)src + (size_t)(i0 + r) * srcStride + srcColOff + j0 + ch*8);
            *(uint4*)&tile[r * 72 + ch*8] = w;
        } else {
            const float* s = (const float*)src + (size_t)(i0 + r) * srcStride + srcColOff + j0 + ch*8;
            float4 a0 = *(const float4*)s;
            float4 a1 = *(const float4*)(s + 4);
            uint4 o;
            o.x = pack2(a0.x, a0.y); o.y = pack2(a0.z, a0.w);
            o.z = pack2(a1.x, a1.y); o.w = pack2(a1.z, a1.w);
            *(uint4*)&tile[r * 72 + ch*8] = o;
        }
    }
    __syncthreads();
    #pragma unroll
    for (int p = 0; p < 2; ++p) {
        const int e = tid + p * 256;
        const int c = e >> 3, ch = e & 7;
        u16 tmp[8];
        #pragma unroll
        for (int j = 0; j < 8; ++j) tmp[j] = tile[(ch*8 + j) * 72 + c];
        *(uint4*)(dst + (size_t)(dstRowOff + j0 + c) * D_ + i0 + ch*8) = *(uint4*)tmp;
    }
}

// ---------------------------------------------------------------------------
// Kernel 1 (R15): MFMA gemm1  xb(4096,1024) @ WcatT^T -> ql/kl + v_t.
// 128x128 tile, BK=64, m97 structure: global_load_lds width=16 direct
// staging into UNPADDED [128][64] tiles. 8 gload/thread/k-iter replaces
// 8 uint4 loads + 8 ds_writes + addr VALU. Grid (16,32)=512 blocks, 2/CU.
// ---------------------------------------------------------------------------
__global__ __launch_bounds__(256, 2) void gemm1_mfma(
    const u16* __restrict__ xb, const u16* __restrict__ WcatT,
    u16* __restrict__ ql, u16* __restrict__ kl, u16* __restrict__ v_t)
{
    __shared__ __align__(16) u16 As[128 * 64];   // 16384 B, linear
    __shared__ __align__(16) u16 Bs[128 * 64];   // 16384 B, linear
    const int tid  = threadIdx.x;
    const int lane = tid & 63;
    const int w    = tid >> 6;
    const int n16  = lane & 15;
    const int q4   = lane >> 4;
    const int wx   = w & 1;          // n-half (64 cols)
    const int wy   = w >> 1;         // m-half (64 rows)
    const int bm   = blockIdx.y * 128;
    const int bn   = blockIdx.x * 128;
    const int lrow = lane >> 3;          // 0..7: row within 8-row stripe
    const int lcol = (lane & 7) * 8;     // u16 col within 64-col row

    floatx4 acc[4][4];
    #pragma unroll
    for (int i = 0; i < 4; ++i)
        #pragma unroll
        for (int j = 0; j < 4; ++j) acc[i][j] = (floatx4)(0.f);

    for (int kt = 0; kt < D_; kt += 64) {
        // stage: wave w covers rows w*32 .. w*32+31 (4 stripes of 8 rows)
        #pragma unroll
        for (int i = 0; i < 4; ++i) {
            const int r0 = w*32 + i*8;
            gload16(xb    + (size_t)(bm + r0 + lrow) * D_ + kt + lcol, &As[r0 * 64]);
            gload16(WcatT + (size_t)(bn + r0 + lrow) * D_ + kt + lcol, &Bs[r0 * 64]);
        }
        __syncthreads();
        #pragma unroll
        for (int kk = 0; kk < 2; ++kk) {
            bhalf8 a[4], b[4];
            #pragma unroll
            for (int mi = 0; mi < 4; ++mi)
                a[mi] = *(const bhalf8*)&As[(wy*64 + mi*16 + n16) * 64 + kk*32 + q4*8];
            #pragma unroll
            for (int ni = 0; ni < 4; ++ni)
                b[ni] = *(const bhalf8*)&Bs[(wx*64 + ni*16 + n16) * 64 + kk*32 + q4*8];
            #pragma unroll
            for (int mi = 0; mi < 4; ++mi)
                #pragma unroll
                for (int ni = 0; ni < 4; ++ni)
                    acc[mi][ni] = __builtin_amdgcn_mfma_f32_16x16x32_bf16(
                        a[mi], b[ni], acc[mi][ni], 0, 0, 0);
        }
        __syncthreads();
    }

    if (bn < 1024) {
        #pragma unroll
        for (int mi = 0; mi < 4; ++mi) {
            #pragma unroll
            for (int rr = 0; rr < 4; ++rr) {
                const int row = bm + wy*64 + mi*16 + q4*4 + rr;
                const int b   = row >> 11;
                const int t   = row & (T_ - 1);
                #pragma unroll
                for (int ni = 0; ni < 4; ++ni) {
                    const int col = bn + wx*64 + ni*16 + n16;
                    const u16 val = tob(acc[mi][ni][rr]);
                    if (col < 512) {
                        const int h = col >> 5, r = col & 31;
                        ql[((size_t)(b*H_ + h)*T_ + t)*R_ + r] = val;
                    } else {
                        const int c = col - 512; const int h = c >> 5, r = c & 31;
                        kl[((size_t)(b*H_ + h)*T_ + t)*R_ + r] = val;
                    }
                }
            }
        }
    } else {
        // v: write v_t (B,H,DH,T) directly — 4 consecutive t pack into 8B
        #pragma unroll
        for (int mi = 0; mi < 4; ++mi) {
            const int row0 = bm + wy*64 + mi*16 + q4*4;
            const int b = row0 >> 11;
            const int t = row0 & (T_ - 1);
            #pragma unroll
            for (int ni = 0; ni < 4; ++ni) {
                const int c = bn - 1024 + wx*64 + ni*16 + n16;
                const int h = c >> 6, dh = c & 63;
                uint2 o;
                o.x = pack2(acc[mi][ni][0], acc[mi][ni][1]);
                o.y = pack2(acc[mi][ni][2], acc[mi][ni][3]);
                *(uint2*)(v_t + ((size_t)(b*H_ + h) * DH_ + dh) * T_ + t) = o;
            }
        }
    }
}

// ---------------------------------------------------------------------------
// softmax update for one 16-row q-group (R13-verified logic, refactored).
// ---------------------------------------------------------------------------
__device__ __forceinline__ void softmax_update(
    floatx4 (&Sc)[8], float &mrow, float &lrow, floatx4 (&O)[4], int q4)
{
    float cmax[8];
    #pragma unroll
    for (int c = 0; c < 8; ++c)
        cmax[c] = fmaxf(fmaxf(Sc[c][0], Sc[c][1]), fmaxf(Sc[c][2], Sc[c][3]));
    float rmax = fmaxf(fmaxf(fmaxf(cmax[0], cmax[1]), fmaxf(cmax[2], cmax[3])),
                       fmaxf(fmaxf(cmax[4], cmax[5]), fmaxf(cmax[6], cmax[7])));
    rmax = fmaxf(rmax, __shfl_xor(rmax, 16, 64));
    rmax = fmaxf(rmax, __shfl_xor(rmax, 32, 64));

    const float mn = fmaxf(mrow, rmax);
    const int norescale = __all(rmax <= mrow);     // exact: alpha == 1

    float csum[8];
    #pragma unroll
    for (int c = 0; c < 8; ++c) {
        #pragma unroll
        for (int r = 0; r < 4; ++r)
            Sc[c][r] = __builtin_amdgcn_exp2f(Sc[c][r] - mn);
        csum[c] = (Sc[c][0] + Sc[c][1]) + (Sc[c][2] + Sc[c][3]);
    }
    float rsum = ((csum[0] + csum[1]) + (csum[2] + csum[3]))
               + ((csum[4] + csum[5]) + (csum[6] + csum[7]));
    rsum += __shfl_xor(rsum, 16, 64);
    rsum += __shfl_xor(rsum, 32, 64);

    if (norescale) {
        lrow += rsum;                              // mn == mrow exactly
    } else {
        const float alpha = __builtin_amdgcn_exp2f(mrow - mn);
        mrow = mn;
        lrow = lrow * alpha + rsum;
        float aO[4];
        #pragma unroll
        for (int r = 0; r < 4; ++r) aO[r] = __shfl(alpha, q4*4 + r, 64);
        #pragma unroll
        for (int c2 = 0; c2 < 4; ++c2)
            #pragma unroll
            for (int r = 0; r < 4; ++r) O[c2][r] *= aO[r];
    }
}

// ---------------------------------------------------------------------------
// Kernel 2 (R14): swapped-QK flash attention, 512-thr blocks, 128-row
// q-tiles. 8 waves x 16 q-rows; one K/V staging serves all 8 waves.
// Zero-LDS P path via sigma-permuted vsT (R13). Uniform per-CU work:
// qt2=(by<8)?15-by:by-8 makes co-resident pair (b, b+256) complementary.
// ---------------------------------------------------------------------------
__global__ __launch_bounds__(512, 4) void attn_kernel(
    const u16* __restrict__ ql, const u16* __restrict__ kl,
    const u16* __restrict__ v_t, u16* __restrict__ y)
{
    __shared__ __align__(16) u16 kls[128 * 40];      // 10240 B
    __shared__ __align__(16) u16 vsT[64 * 136];      // 17408 B, sigma-permuted

    const int tid  = threadIdx.x;
    const int lane = tid & 63;
    const int w    = tid >> 6;               // 0..7
    const int n16  = lane & 15;
    const int q4   = lane >> 4;
    const int bh   = blockIdx.x;
    const int by   = blockIdx.y;             // 0..15
    const int qt2  = (by < 8) ? (15 - by) : (by - 8);  // complementary pairs
    const int t0   = qt2 * 128;
    const int nt   = qt2 + 1;                // # of 128-wide s-tiles

    // Q fragment = B-operand of swapped QK^T; loads directly in frag layout.
    const u16* qlb = ql + (size_t)bh * T_ * R_;
    const bhalf8 aq = *(const bhalf8*)(qlb + (size_t)(t0 + w*16 + n16) * R_ + q4*8);

    const u16* klb = kl  + (size_t)bh * T_ * R_;
    const u16* vtb = v_t + (size_t)bh * DH_ * T_;
    const int rk = tid >> 2, ck = (tid & 3) * 8;   // kls: 128 rows x 32, 1 b128/thread
    const int dv = tid >> 4;                       // vsT rows dv, dv+32
    const int m  = tid & 15;
    const int cv = m * 8;
    // sigma staging base: 8 consecutive s (=8m+i) -> two uint2 at pb, pb+8.
    const int pb = ((m & 1) << 4) | (((m >> 1) & 1) << 2) | ((m >> 2) << 5);

    uint4 kc0 = *(const uint4*)(klb + (size_t)(rk     ) * R_ + ck);
    uint4 vc0 = *(const uint4*)(vtb + (size_t)(dv     ) * T_ + cv);
    uint4 vc1 = *(const uint4*)(vtb + (size_t)(dv + 32) * T_ + cv);
    uint4 kn0 = kc0, vn0 = vc0, vn1 = vc1;

    float mrow = NEG_, lrow = 0.f;           // one q-row per lane
    floatx4 O[4];
    #pragma unroll
    for (int c = 0; c < 4; ++c) O[c] = (floatx4)(0.f);

    for (int it = 0; it < nt; ++it) {
        const int s0 = it * 128;
        __syncthreads();
        *(uint4*)&kls[rk * 40 + ck] = kc0;
        {
            uint2 t;
            t.x = vc0.x; t.y = vc0.y; *(uint2*)&vsT[(dv     ) * 136 + pb    ] = t;
            t.x = vc0.z; t.y = vc0.w; *(uint2*)&vsT[(dv     ) * 136 + pb + 8] = t;
            t.x = vc1.x; t.y = vc1.y; *(uint2*)&vsT[(dv + 32) * 136 + pb    ] = t;
            t.x = vc1.z; t.y = vc1.w; *(uint2*)&vsT[(dv + 32) * 136 + pb + 8] = t;
        }
        if (it + 1 < nt) {
            const int s1 = s0 + 128;
            kn0 = *(const uint4*)(klb + (size_t)(s1 + rk) * R_ + ck);
            vn0 = *(const uint4*)(vtb + (size_t)(dv     ) * T_ + s1 + cv);
            vn1 = *(const uint4*)(vtb + (size_t)(dv + 32) * T_ + s1 + cv);
        }
        __syncthreads();

        // S^T: A = K-frag (m=s), B = Q-frag (n=q). Lane: q=n16, s=16c+4q4+r.
        floatx4 Sc[8];
        #pragma unroll
        for (int c = 0; c < 8; ++c) {
            bhalf8 ak = *(const bhalf8*)&kls[(16*c + n16) * 40 + q4*8];
            Sc[c] = __builtin_amdgcn_mfma_f32_16x16x32_bf16(ak, aq, (floatx4)(0.f), 0, 0, 0);
        }

        if (it == nt - 1) {
            const int tq = w*16 + n16;                 // local q row (0..127)
            #pragma unroll
            for (int c = 0; c < 8; ++c) {
                const int sb = 16*c + 4*q4;            // local s base (s0==t0)
                #pragma unroll
                for (int r = 0; r < 4; ++r)
                    if (sb + r > tq) Sc[c][r] = NEG_;
            }
        }

        softmax_update(Sc, mrow, lrow, O, q4);

        // PV: A-frag slot (kc,q4,j) must hold P[q][s=32kc+16(j>>2)+4q4+(j&3)]
        // = lane's own Sc[c=2kc+(j>>2)][r=j&3]. Pack in-register, no LDS.
        #pragma unroll
        for (int kc = 0; kc < 4; ++kc) {
            union { u32 wd[4]; bhalf8 v; } pu;
            pu.wd[0] = pack2(Sc[2*kc    ][0], Sc[2*kc    ][1]);
            pu.wd[1] = pack2(Sc[2*kc    ][2], Sc[2*kc    ][3]);
            pu.wd[2] = pack2(Sc[2*kc + 1][0], Sc[2*kc + 1][1]);
            pu.wd[3] = pack2(Sc[2*kc + 1][2], Sc[2*kc + 1][3]);
            const bhalf8 pa = pu.v;
            #pragma unroll
            for (int c2 = 0; c2 < 4; ++c2) {
                bhalf8 bv = *(const bhalf8*)&vsT[(16*c2 + n16) * 136 + kc*32 + q4*8];
                O[c2] = __builtin_amdgcn_mfma_f32_16x16x32_bf16(pa, bv, O[c2], 0, 0, 0);
            }
        }

        kc0 = kn0; vc0 = vn0; vc1 = vn1;
    }

    // Epilogue: broadcast l from row-owner lanes (q = q4*4+r lives in lane q).
    const int b = bh >> 4, h = bh & 15;
    float lb[4];
    #pragma unroll
    for (int r = 0; r < 4; ++r) lb[r] = __shfl(lrow, q4*4 + r, 64);
    #pragma unroll
    for (int r = 0; r < 4; ++r) {
        const float rl = 1.0f / lb[r];
        const int t = t0 + w*16 + q4*4 + r;
        #pragma unroll
        for (int c2 = 0; c2 < 4; ++c2)
            y[((size_t)b * T_ + t) * D_ + h * DH_ + 16*c2 + n16] = tob(O[c2][r] * rl);
    }
}

// ---------------------------------------------------------------------------
// Kernel 3 (R15): MFMA out-gemm  yb(4096,1024) @ WoT^T -> out fp32.
// m97 structure: global_load_lds staging, unpadded tiles. 128x64, 512 blocks.
// ---------------------------------------------------------------------------
__global__ __launch_bounds__(256, 2) void out_gemm_mfma(
    const u16* __restrict__ yb, const u16* __restrict__ WoT,
    float* __restrict__ out)
{
    __shared__ __align__(16) u16 As[128 * 64];   // linear
    __shared__ __align__(16) u16 Bs[64 * 64];    // linear
    const int tid  = threadIdx.x;
    const int lane = tid & 63;
    const int w    = tid >> 6;
    const int n16  = lane & 15;
    const int q4   = lane >> 4;
    const int wx   = w & 1;
    const int wy   = w >> 1;
    const int bm   = blockIdx.y * 128;
    const int bn   = blockIdx.x * 64;
    const int lrow = lane >> 3;
    const int lcol = (lane & 7) * 8;

    floatx4 acc[4][2];
    #pragma unroll
    for (int i = 0; i < 4; ++i)
        #pragma unroll
        for (int j = 0; j < 2; ++j) acc[i][j] = (floatx4)(0.f);

    for (int kt = 0; kt < D_; kt += 64) {
        #pragma unroll
        for (int i = 0; i < 4; ++i) {
            const int r0 = w*32 + i*8;
            gload16(yb + (size_t)(bm + r0 + lrow) * D_ + kt + lcol, &As[r0 * 64]);
        }
        #pragma unroll
        for (int i = 0; i < 2; ++i) {
            const int r0 = w*16 + i*8;
            gload16(WoT + (size_t)(bn + r0 + lrow) * D_ + kt + lcol, &Bs[r0 * 64]);
        }
        __syncthreads();
        #pragma unroll
        for (int kk = 0; kk < 2; ++kk) {
            bhalf8 a[4], b[2];
            #pragma unroll
            for (int mi = 0; mi < 4; ++mi)
                a[mi] = *(const bhalf8*)&As[(wy*64 + mi*16 + n16) * 64 + kk*32 + q4*8];
            #pragma unroll
            for (int ni = 0; ni < 2; ++ni)
                b[ni] = *(const bhalf8*)&Bs[(wx*32 + ni*16 + n16) * 64 + kk*32 + q4*8];
            #pragma unroll
            for (int mi = 0; mi < 4; ++mi)
                #pragma unroll
                for (int ni = 0; ni < 2; ++ni)
                    acc[mi][ni] = __builtin_amdgcn_mfma_f32_16x16x32_bf16(
                        a[mi], b[ni], acc[mi][ni], 0, 0, 0);
        }
        __syncthreads();
    }

    #pragma unroll
    for (int mi = 0; mi < 4; ++mi) {
        #pragma unroll
        for (int rr = 0; rr < 4; ++rr) {
            const int row = bm + wy*64 + mi*16 + q4*4 + rr;
            #pragma unroll
            for (int ni = 0; ni < 2; ++ni) {
                const int col = bn + wx*32 + ni*16 + n16;
                out[(size_t)row * D_ + col] = acc[mi][ni][rr];
            }
        }
    }
}

// ---------------------------------------------------------------------------
extern "C" void kernel_launch(void* const* d_in, const int* in_sizes, int n_in,
                              void* d_out, int out_size, void* d_ws, size_t ws_size,
                              hipStream_t stream)
{
    (void)out_size; (void)ws_size;
    const void* in_x = nullptr; const void* in_wqkv = nullptr;
    const void* in_wq = nullptr; const void* in_wk = nullptr;
    const void* in_core = nullptr; const void* in_wo = nullptr;
    for (int i = 0; i < n_in; ++i) {
        const int s = in_sizes[i];
        if      (s == BT_*D_)     { if (!in_x)    in_x    = d_in[i]; }
        else if (s == D_*3*D_)    { if (!in_wqkv) in_wqkv = d_in[i]; }
        else if (s == H_*DH_*R_)  { if (!in_wq)   in_wq   = d_in[i]; else if (!in_wk) in_wk = d_in[i]; }
        else if (s == H_*R_)      { if (!in_core) in_core = d_in[i]; }
        else if (s == D_*D_)      { if (!in_wo)   in_wo   = d_in[i]; }
    }
    if (!in_x)    in_x    = d_in[0];
    if (!in_wqkv) in_wqkv = d_in[1];
    if (!in_wq)   in_wq   = d_in[2];
    if (!in_wk)   in_wk   = d_in[3];
    if (!in_core) in_core = d_in[4];
    if (!in_wo)   in_wo   = d_in[5];

    float* out = (float*)d_out;

    char* ws    = (char*)d_ws;
    int*  flag  = (int*)(ws + WSB_FLAG);
    u16*  xb    = (u16*)(ws + WSB_XB);
    u16*  WcatT = (u16*)(ws + WSB_WCATT);
    u16*  ql    = (u16*)(ws + WSB_QL);
    u16*  kl    = (u16*)(ws + WSB_KL);
    u16*  v_t   = (u16*)(ws + WSB_VT);
    u16*  yb    = (u16*)(ws + WSB_YB);
    u16*  WoT   = (u16*)(ws + WSB_WOT);

    detect_dtype<<<1, 64, 0, stream>>>((const u32*)in_x, flag);
    convert_x<<<2048, 256, 0, stream>>>(in_x, xb, flag);
    fold_mfma<<<dim3(8, 16), 256, 0, stream>>>(in_wqkv, in_wq, in_wk, in_core, WcatT, flag);
    convert_T<<<dim3(16,16), 256, 0, stream>>>(in_wqkv, WcatT, 3*D_, 2*D_, 1024, flag); // W_v
    convert_T<<<dim3(16,16), 256, 0, stream>>>(in_wo,   WoT,   D_,   0,    0,    flag); // W_o
    gemm1_mfma<<<dim3(16, 32), 256, 0, stream>>>(xb, WcatT, ql, kl, v_t);
    attn_kernel<<<dim3(32, 16), 512, 0, stream>>>(ql, kl, v_t, yb);
    out_gemm_mfma<<<dim3(16, 32), 256, 0, stream>>>(yb, WoT, out);
}

// Round 5
// 183.012 us; speedup vs baseline: 1.0356x; 1.0111x over previous
//
#include <hip/hip_runtime.h>
#include <hip/hip_bf16.h>

// Established rounds 0-10: inputs fp32 (detector=insurance), output fp32.
// R5/R6: VALU->MFMA. R8: fold -> MFMA. R10 LESSON: reg prefetch before a
// __syncthreads is DEFEATED (barrier emits s_waitcnt vmcnt(0)). R11: direct
// stage->LDS, TLP 4 blocks/CU. R12: swapped-QK attn (lane-local softmax,
// exp2, rescale-skip). R13: zero-LDS P path via sigma-permuted V. R14: attn
// 512-thr/128-row q-tiles complementary pairing; gemm1 128x128 (512 blocks
// — TLP REGRESSION, unisolated). R15: gload_lds staging both GEMMs: FLAT.
// Post-mortem: gemm1 is grid-starved at 2 blocks/CU (m97's 874 TF needs 4;
// m114 overlap needs >=3 resident); also ~40us of the 185 is unaccounted —
// suspect harness workspace fill inside timed region + 8 launch gaps.
// R16 (this round):
//  - gemm1 back to 128x64 / 1024 blocks / 4 per CU (R11 TLP) + gload16.
//  - out_gemm 64x64 / 1024 blocks / 4 per CU + gload16.
//  - dispatches 8->5: detect_dtype inlined (wave-level, reads 2KB of x),
//    convert_x + convert_T(Wv) + convert_T(Wo) fused into one kernel.
// Pre-committed read: if total flat again, the fill is the floor term;
// R17 goes at attn VALU softmax.
#define B_  2
#define T_  2048
#define D_  1024
#define H_  16
#define DH_ 64
#define R_  32
#define BT_ (B_*T_)          // 4096
#define BH_ (B_*H_)          // 32

typedef unsigned short u16;
typedef unsigned int   u32;
typedef __attribute__((ext_vector_type(8))) short bhalf8;   // 8 bf16 = 4 VGPRs
typedef __attribute__((ext_vector_type(4))) float floatx4;  // MFMA C/D

// Workspace layout (bytes). Total ~38 MB.
#define WSB_FLAG  0
#define WSB_XB    256                        // bf16 x     (4096,1024)  8 MB
#define WSB_WCATT (WSB_XB    + 8388608)      // bf16 WcatT (2048,1024)  4 MB
#define WSB_QL    (WSB_WCATT + 4194304)      // bf16 (B,H,T,R)          4 MB
#define WSB_KL    (WSB_QL    + 4194304)      // bf16 (B,H,T,R)          4 MB
#define WSB_VT    (WSB_KL    + 4194304)      // bf16 (B,H,DH,T)         8 MB
#define WSB_YB    (WSB_VT    + 8388608)      // bf16 y     (B,T,D)      8 MB
#define WSB_WOT   (WSB_YB    + 8388608)      // bf16 WoT   (1024,1024)  2 MB

#define NEG_ -1.0e30f

__device__ __forceinline__ float bfs(u16 s) {
    union { u32 i; float f; } w; w.i = ((u32)s) << 16; return w.f;
}
__device__ __forceinline__ u16 tob(float f) {
    __hip_bfloat16 h = __float2bfloat16(f);   // RNE
    return *(u16*)&h;
}
__device__ __forceinline__ u32 pack2(float a, float b) {
    return (u32)tob(a) | ((u32)tob(b) << 16);
}
// Direct global->LDS staging, 16B/lane. LDS base must be wave-uniform;
// HW writes base + lane*16. Global address is per-lane.
__device__ __forceinline__ void gload16(const u16* g, u16* l) {
    __builtin_amdgcn_global_load_lds(
        (const __attribute__((address_space(1))) void*)g,
        (__attribute__((address_space(3))) void*)l, 16, 0, 0);
}
// Inline dtype detect (1 = bf16, 0 = fp32) from first 2KB of x. Wave-level;
// every wave computes (8 L2-hit loads/lane), result broadcast to all lanes.
__device__ __forceinline__ int detect_isbf(const u32* __restrict__ xw, int lane) {
    int hits = 0;
    #pragma unroll
    for (int i = 0; i < 8; ++i) {
        const u32 w = xw[lane + i * 64];
        const u32 h = w & 0xFFFFu;
        const u32 e = (h >> 7) & 0xFFu;
        if (h == 0u || (e >= 100u && e <= 150u)) ++hits;
    }
    #pragma unroll
    for (int off = 32; off; off >>= 1) hits += __shfl_down(hits, off, 64);
    return __shfl(hits, 0, 64) >= 300;
}

// ---------------------------------------------------------------------------
// Kernel C (R16): fused converts. Blocks 0..2047: x -> xb bf16 (8/thread).
// Blocks 2048..2303: transposing convert W_v slice of Wqkv -> WcatT[1024..].
// Blocks 2304..2559: transposing convert W_o -> WoT.
// ---------------------------------------------------------------------------
__global__ __launch_bounds__(256) void convert_fused(
    const void* __restrict__ x, u16* __restrict__ xb,
    const void* __restrict__ Wqkv, const void* __restrict__ Wo,
    u16* __restrict__ WcatT, u16* __restrict__ WoT)
{
    __shared__ __align__(16) u16 tile[64 * 72];
    const int tid  = threadIdx.x;
    const int lane = tid & 63;
    const int isbf = detect_isbf((const u32*)x, lane);
    const int blk  = blockIdx.x;

    if (blk < 2048) {
        const int e = blk * 256 + tid;           // over 524288 (x8 elems)
        if (isbf) {
            ((uint4*)xb)[e] = ((const uint4*)x)[e];
        } else {
            float4 a0 = ((const float4*)x)[2*e];
            float4 a1 = ((const float4*)x)[2*e + 1];
            uint4 o;
            o.x = pack2(a0.x, a0.y); o.y = pack2(a0.z, a0.w);
            o.z = pack2(a1.x, a1.y); o.w = pack2(a1.z, a1.w);
            ((uint4*)xb)[e] = o;
        }
        return;
    }

    int t = blk - 2048;
    const void* src; u16* dst; int srcStride, srcColOff, dstRowOff;
    if (t < 256) { src = Wqkv; dst = WcatT; srcStride = 3*D_; srcColOff = 2*D_; dstRowOff = 1024; }
    else { t -= 256; src = Wo; dst = WoT; srcStride = D_; srcColOff = 0; dstRowOff = 0; }
    const int j0 = (t & 15) * 64;
    const int i0 = (t >> 4) * 64;
    #pragma unroll
    for (int p = 0; p < 2; ++p) {
        const int e = tid + p * 256;
        const int r = e >> 3, ch = e & 7;
        if (isbf) {
            uint4 w = *(const uint4*)((const u16*)src + (size_t)(i0 + r) * srcStride + srcColOff + j0 + ch*8);
            *(uint4*)&tile[r * 72 + ch*8] = w;
        } else {
            const float* s = (const float*)src + (size_t)(i0 + r) * srcStride + srcColOff + j0 + ch*8;
            float4 a0 = *(const float4*)s;
            float4 a1 = *(const float4*)(s + 4);
            uint4 o;
            o.x = pack2(a0.x, a0.y); o.y = pack2(a0.z, a0.w);
            o.z = pack2(a1.x, a1.y); o.w = pack2(a1.z, a1.w);
            *(uint4*)&tile[r * 72 + ch*8] = o;
        }
    }
    __syncthreads();
    #pragma unroll
    for (int p = 0; p < 2; ++p) {
        const int e = tid + p * 256;
        const int c = e >> 3, ch = e & 7;
        u16 tmp[8];
        #pragma unroll
        for (int j = 0; j < 8; ++j) tmp[j] = tile[(ch*8 + j) * 72 + c];
        *(uint4*)(dst + (size_t)(dstRowOff + j0 + c) * D_ + i0 + ch*8) = *(uint4*)tmp;
    }
}

// ---------------------------------------------------------------------------
// Kernel 0: fold via MFMA. Per head h: Cq(32x1024) = Aq_h^T(32x64) @ Wq_h(64x1024)
// with m=r, k=dh, n=d. Scale folds 1/sqrt(32) * log2(e) (exp2-domain attn).
// R16: dtype detect inlined (reads x's first 2KB).
// ---------------------------------------------------------------------------
__global__ __launch_bounds__(256) void fold_mfma(
    const void* __restrict__ Wqkv, const void* __restrict__ Wq_lsr,
    const void* __restrict__ Wk_lsr, const void* __restrict__ core,
    u16* __restrict__ WcatT, const void* __restrict__ x)
{
    __shared__ __align__(16) u16 Bq[128 * 72];   // [n=d][k=dh]
    __shared__ __align__(16) u16 Bk[128 * 72];
    __shared__ __align__(16) u16 Aq[32 * 72];    // [m=r][k=dh]
    __shared__ __align__(16) u16 Ak[32 * 72];
    const int tid  = threadIdx.x;
    const int lane = tid & 63;
    const int isbf = detect_isbf((const u32*)x, lane);
    const int w    = tid >> 6;
    const int n16  = lane & 15;
    const int q4   = lane >> 4;
    const int h    = blockIdx.y;        // 0..15
    const int d0   = blockIdx.x * 128;  // 0..896

    #pragma unroll
    for (int p = 0; p < 8; ++p) {
        const int e  = tid + p * 256;
        const int r  = e & 31, dh = e >> 5;
        float aq, ak;
        if (isbf) {
            aq = bfs(((const u16*)Wq_lsr)[(h*DH_ + dh)*R_ + r]);
            ak = bfs(((const u16*)Wk_lsr)[(h*DH_ + dh)*R_ + r]);
        } else {
            aq = ((const float*)Wq_lsr)[(h*DH_ + dh)*R_ + r];
            ak = ((const float*)Wk_lsr)[(h*DH_ + dh)*R_ + r];
        }
        Aq[r * 72 + dh] = tob(aq);
        Ak[r * 72 + dh] = tob(ak);
    }
    #pragma unroll
    for (int p = 0; p < 8; ++p) {
        const int e  = tid + p * 256;      // 0..2047
        const int n  = e >> 4, ch = e & 15;
        if (isbf) {
            uint2 wq = *(const uint2*)((const u16*)Wqkv + (size_t)(d0+n)*(3*D_) + h*DH_ + ch*4);
            uint2 wk = *(const uint2*)((const u16*)Wqkv + (size_t)(d0+n)*(3*D_) + D_ + h*DH_ + ch*4);
            *(uint2*)&Bq[n * 72 + ch*4] = wq;
            *(uint2*)&Bk[n * 72 + ch*4] = wk;
        } else {
            float4 fq = *(const float4*)((const float*)Wqkv + (size_t)(d0+n)*(3*D_) + h*DH_ + ch*4);
            float4 fk = *(const float4*)((const float*)Wqkv + (size_t)(d0+n)*(3*D_) + D_ + h*DH_ + ch*4);
            uint2 oq, ok;
            oq.x = pack2(fq.x, fq.y); oq.y = pack2(fq.z, fq.w);
            ok.x = pack2(fk.x, fk.y); ok.y = pack2(fk.z, fk.w);
            *(uint2*)&Bq[n * 72 + ch*4] = oq;
            *(uint2*)&Bk[n * 72 + ch*4] = ok;
        }
    }
    __syncthreads();

    floatx4 accq[2][2], acck[2][2];
    #pragma unroll
    for (int mi = 0; mi < 2; ++mi)
        #pragma unroll
        for (int ni = 0; ni < 2; ++ni) { accq[mi][ni] = (floatx4)(0.f); acck[mi][ni] = (floatx4)(0.f); }

    #pragma unroll
    for (int kk = 0; kk < 2; ++kk) {
        bhalf8 aqf[2], akf[2], bqf[2], bkf[2];
        #pragma unroll
        for (int mi = 0; mi < 2; ++mi) {
            aqf[mi] = *(const bhalf8*)&Aq[(mi*16 + n16) * 72 + kk*32 + q4*8];
            akf[mi] = *(const bhalf8*)&Ak[(mi*16 + n16) * 72 + kk*32 + q4*8];
        }
        #pragma unroll
        for (int ni = 0; ni < 2; ++ni) {
            bqf[ni] = *(const bhalf8*)&Bq[(w*32 + ni*16 + n16) * 72 + kk*32 + q4*8];
            bkf[ni] = *(const bhalf8*)&Bk[(w*32 + ni*16 + n16) * 72 + kk*32 + q4*8];
        }
        #pragma unroll
        for (int mi = 0; mi < 2; ++mi)
            #pragma unroll
            for (int ni = 0; ni < 2; ++ni) {
                accq[mi][ni] = __builtin_amdgcn_mfma_f32_16x16x32_bf16(aqf[mi], bqf[ni], accq[mi][ni], 0, 0, 0);
                acck[mi][ni] = __builtin_amdgcn_mfma_f32_16x16x32_bf16(akf[mi], bkf[ni], acck[mi][ni], 0, 0, 0);
            }
    }

    // 1/sqrt(32) * log2(e): softmax done in exp2 domain (native v_exp_f32).
    const float scale = (float)(0.17677669529663687 * 1.4426950408889634);
    #pragma unroll
    for (int mi = 0; mi < 2; ++mi) {
        #pragma unroll
        for (int rr = 0; rr < 4; ++rr) {
            const int r = mi*16 + q4*4 + rr;
            const float cc = (isbf ? bfs(((const u16*)core)[h*R_ + r])
                                   : ((const float*)core)[h*R_ + r]) * scale;
            #pragma unroll
            for (int ni = 0; ni < 2; ++ni) {
                const int d = d0 + w*32 + ni*16 + n16;
                WcatT[(size_t)(h*R_ + r) * D_ + d]       = tob(accq[mi][ni][rr] * cc);
                WcatT[(size_t)(512 + h*R_ + r) * D_ + d] = tob(acck[mi][ni][rr]);
            }
        }
    }
}

// ---------------------------------------------------------------------------
// Kernel 1 (R16): MFMA gemm1  xb(4096,1024) @ WcatT^T -> ql/kl + v_t.
// 128x64 tile, BK=64 (R11 TLP shape), gload16 staging into linear LDS.
// Grid (32,32) = 1024 blocks = 4/CU. 6 gloads/thread/k-iter, 16 MFMA/wave.
// ---------------------------------------------------------------------------
__global__ __launch_bounds__(256, 4) void gemm1_mfma(
    const u16* __restrict__ xb, const u16* __restrict__ WcatT,
    u16* __restrict__ ql, u16* __restrict__ kl, u16* __restrict__ v_t)
{
    __shared__ __align__(16) u16 As[128 * 64];   // 16384 B, linear
    __shared__ __align__(16) u16 Bs[64 * 64];    //  8192 B, linear
    const int tid  = threadIdx.x;
    const int lane = tid & 63;
    const int w    = tid >> 6;
    const int n16  = lane & 15;
    const int q4   = lane >> 4;
    const int wx   = w & 1;          // n-half (32 cols)
    const int wy   = w >> 1;         // m-half (64 rows)
    const int bm   = blockIdx.y * 128;
    const int bn   = blockIdx.x * 64;
    const int lrow = lane >> 3;          // 0..7: row within 8-row stripe
    const int lcol = (lane & 7) * 8;     // u16 col within 64-col row

    floatx4 acc[4][2];
    #pragma unroll
    for (int i = 0; i < 4; ++i)
        #pragma unroll
        for (int j = 0; j < 2; ++j) acc[i][j] = (floatx4)(0.f);

    for (int kt = 0; kt < D_; kt += 64) {
        // A: wave w rows w*32..w*32+31 (4 stripes); B: wave w rows w*16..+15.
        #pragma unroll
        for (int i = 0; i < 4; ++i) {
            const int r0 = w*32 + i*8;
            gload16(xb + (size_t)(bm + r0 + lrow) * D_ + kt + lcol, &As[r0 * 64]);
        }
        #pragma unroll
        for (int i = 0; i < 2; ++i) {
            const int r0 = w*16 + i*8;
            gload16(WcatT + (size_t)(bn + r0 + lrow) * D_ + kt + lcol, &Bs[r0 * 64]);
        }
        __syncthreads();
        #pragma unroll
        for (int kk = 0; kk < 2; ++kk) {
            bhalf8 a[4], b[2];
            #pragma unroll
            for (int mi = 0; mi < 4; ++mi)
                a[mi] = *(const bhalf8*)&As[(wy*64 + mi*16 + n16) * 64 + kk*32 + q4*8];
            #pragma unroll
            for (int ni = 0; ni < 2; ++ni)
                b[ni] = *(const bhalf8*)&Bs[(wx*32 + ni*16 + n16) * 64 + kk*32 + q4*8];
            #pragma unroll
            for (int mi = 0; mi < 4; ++mi)
                #pragma unroll
                for (int ni = 0; ni < 2; ++ni)
                    acc[mi][ni] = __builtin_amdgcn_mfma_f32_16x16x32_bf16(
                        a[mi], b[ni], acc[mi][ni], 0, 0, 0);
        }
        __syncthreads();
    }

    if (bn < 1024) {
        #pragma unroll
        for (int mi = 0; mi < 4; ++mi) {
            #pragma unroll
            for (int rr = 0; rr < 4; ++rr) {
                const int row = bm + wy*64 + mi*16 + q4*4 + rr;
                const int b   = row >> 11;
                const int t   = row & (T_ - 1);
                #pragma unroll
                for (int ni = 0; ni < 2; ++ni) {
                    const int col = bn + wx*32 + ni*16 + n16;
                    const u16 val = tob(acc[mi][ni][rr]);
                    if (col < 512) {
                        const int h = col >> 5, r = col & 31;
                        ql[((size_t)(b*H_ + h)*T_ + t)*R_ + r] = val;
                    } else {
                        const int c = col - 512; const int h = c >> 5, r = c & 31;
                        kl[((size_t)(b*H_ + h)*T_ + t)*R_ + r] = val;
                    }
                }
            }
        }
    } else {
        // v: write v_t (B,H,DH,T) directly — 4 consecutive t pack into 8B
        #pragma unroll
        for (int mi = 0; mi < 4; ++mi) {
            const int row0 = bm + wy*64 + mi*16 + q4*4;
            const int b = row0 >> 11;
            const int t = row0 & (T_ - 1);
            #pragma unroll
            for (int ni = 0; ni < 2; ++ni) {
                const int c = bn - 1024 + wx*32 + ni*16 + n16;
                const int h = c >> 6, dh = c & 63;
                uint2 o;
                o.x = pack2(acc[mi][ni][0], acc[mi][ni][1]);
                o.y = pack2(acc[mi][ni][2], acc[mi][ni][3]);
                *(uint2*)(v_t + ((size_t)(b*H_ + h) * DH_ + dh) * T_ + t) = o;
            }
        }
    }
}

// ---------------------------------------------------------------------------
// softmax update for one 16-row q-group (R13-verified logic).
// ---------------------------------------------------------------------------
__device__ __forceinline__ void softmax_update(
    floatx4 (&Sc)[8], float &mrow, float &lrow, floatx4 (&O)[4], int q4)
{
    float cmax[8];
    #pragma unroll
    for (int c = 0; c < 8; ++c)
        cmax[c] = fmaxf(fmaxf(Sc[c][0], Sc[c][1]), fmaxf(Sc[c][2], Sc[c][3]));
    float rmax = fmaxf(fmaxf(fmaxf(cmax[0], cmax[1]), fmaxf(cmax[2], cmax[3])),
                       fmaxf(fmaxf(cmax[4], cmax[5]), fmaxf(cmax[6], cmax[7])));
    rmax = fmaxf(rmax, __shfl_xor(rmax, 16, 64));
    rmax = fmaxf(rmax, __shfl_xor(rmax, 32, 64));

    const float mn = fmaxf(mrow, rmax);
    const int norescale = __all(rmax <= mrow);     // exact: alpha == 1

    float csum[8];
    #pragma unroll
    for (int c = 0; c < 8; ++c) {
        #pragma unroll
        for (int r = 0; r < 4; ++r)
            Sc[c][r] = __builtin_amdgcn_exp2f(Sc[c][r] - mn);
        csum[c] = (Sc[c][0] + Sc[c][1]) + (Sc[c][2] + Sc[c][3]);
    }
    float rsum = ((csum[0] + csum[1]) + (csum[2] + csum[3]))
               + ((csum[4] + csum[5]) + (csum[6] + csum[7]));
    rsum += __shfl_xor(rsum, 16, 64);
    rsum += __shfl_xor(rsum, 32, 64);

    if (norescale) {
        lrow += rsum;                              // mn == mrow exactly
    } else {
        const float alpha = __builtin_amdgcn_exp2f(mrow - mn);
        mrow = mn;
        lrow = lrow * alpha + rsum;
        float aO[4];
        #pragma unroll
        for (int r = 0; r < 4; ++r) aO[r] = __shfl(alpha, q4*4 + r, 64);
        #pragma unroll
        for (int c2 = 0; c2 < 4; ++c2)
            #pragma unroll
            for (int r = 0; r < 4; ++r) O[c2][r] *= aO[r];
    }
}

// ---------------------------------------------------------------------------
// Kernel 2 (R14): swapped-QK flash attention, 512-thr blocks, 128-row
// q-tiles. 8 waves x 16 q-rows; one K/V staging serves all 8 waves.
// Zero-LDS P path via sigma-permuted vsT (R13). Uniform per-CU work:
// qt2=(by<8)?15-by:by-8 makes co-resident pair (b, b+256) complementary.
// ---------------------------------------------------------------------------
__global__ __launch_bounds__(512, 4) void attn_kernel(
    const u16* __restrict__ ql, const u16* __restrict__ kl,
    const u16* __restrict__ v_t, u16* __restrict__ y)
{
    __shared__ __align__(16) u16 kls[128 * 40];      // 10240 B
    __shared__ __align__(16) u16 vsT[64 * 136];      // 17408 B, sigma-permuted

    const int tid  = threadIdx.x;
    const int lane = tid & 63;
    const int w    = tid >> 6;               // 0..7
    const int n16  = lane & 15;
    const int q4   = lane >> 4;
    const int bh   = blockIdx.x;
    const int by   = blockIdx.y;             // 0..15
    const int qt2  = (by < 8) ? (15 - by) : (by - 8);  // complementary pairs
    const int t0   = qt2 * 128;
    const int nt   = qt2 + 1;                // # of 128-wide s-tiles

    // Q fragment = B-operand of swapped QK^T; loads directly in frag layout.
    const u16* qlb = ql + (size_t)bh * T_ * R_;
    const bhalf8 aq = *(const bhalf8*)(qlb + (size_t)(t0 + w*16 + n16) * R_ + q4*8);

    const u16* klb = kl  + (size_t)bh * T_ * R_;
    const u16* vtb = v_t + (size_t)bh * DH_ * T_;
    const int rk = tid >> 2, ck = (tid & 3) * 8;   // kls: 128 rows x 32, 1 b128/thread
    const int dv = tid >> 4;                       // vsT rows dv, dv+32
    const int m  = tid & 15;
    const int cv = m * 8;
    // sigma staging base: 8 consecutive s (=8m+i) -> two uint2 at pb, pb+8.
    const int pb = ((m & 1) << 4) | (((m >> 1) & 1) << 2) | ((m >> 2) << 5);

    uint4 kc0 = *(const uint4*)(klb + (size_t)(rk     ) * R_ + ck);
    uint4 vc0 = *(const uint4*)(vtb + (size_t)(dv     ) * T_ + cv);
    uint4 vc1 = *(const uint4*)(vtb + (size_t)(dv + 32) * T_ + cv);
    uint4 kn0 = kc0, vn0 = vc0, vn1 = vc1;

    float mrow = NEG_, lrow = 0.f;           // one q-row per lane
    floatx4 O[4];
    #pragma unroll
    for (int c = 0; c < 4; ++c) O[c] = (floatx4)(0.f);

    for (int it = 0; it < nt; ++it) {
        const int s0 = it * 128;
        __syncthreads();
        *(uint4*)&kls[rk * 40 + ck] = kc0;
        {
            uint2 t;
            t.x = vc0.x; t.y = vc0.y; *(uint2*)&vsT[(dv     ) * 136 + pb    ] = t;
            t.x = vc0.z; t.y = vc0.w; *(uint2*)&vsT[(dv     ) * 136 + pb + 8] = t;
            t.x = vc1.x; t.y = vc1.y; *(uint2*)&vsT[(dv + 32) * 136 + pb    ] = t;
            t.x = vc1.z; t.y = vc1.w; *(uint2*)&vsT[(dv + 32) * 136 + pb + 8] = t;
        }
        if (it + 1 < nt) {
            const int s1 = s0 + 128;
            kn0 = *(const uint4*)(klb + (size_t)(s1 + rk) * R_ + ck);
            vn0 = *(const uint4*)(vtb + (size_t)(dv     ) * T_ + s1 + cv);
            vn1 = *(const uint4*)(vtb + (size_t)(dv + 32) * T_ + s1 + cv);
        }
        __syncthreads();

        // S^T: A = K-frag (m=s), B = Q-frag (n=q). Lane: q=n16, s=16c+4q4+r.
        floatx4 Sc[8];
        #pragma unroll
        for (int c = 0; c < 8; ++c) {
            bhalf8 ak = *(const bhalf8*)&kls[(16*c + n16) * 40 + q4*8];
            Sc[c] = __builtin_amdgcn_mfma_f32_16x16x32_bf16(ak, aq, (floatx4)(0.f), 0, 0, 0);
        }

        if (it == nt - 1) {
            const int tq = w*16 + n16;                 // local q row (0..127)
            #pragma unroll
            for (int c = 0; c < 8; ++c) {
                const int sb = 16*c + 4*q4;            // local s base (s0==t0)
                #pragma unroll
                for (int r = 0; r < 4; ++r)
                    if (sb + r > tq) Sc[c][r] = NEG_;
            }
        }

        softmax_update(Sc, mrow, lrow, O, q4);

        // PV: A-frag slot (kc,q4,j) must hold P[q][s=32kc+16(j>>2)+4q4+(j&3)]
        // = lane's own Sc[c=2kc+(j>>2)][r=j&3]. Pack in-register, no LDS.
        #pragma unroll
        for (int kc = 0; kc < 4; ++kc) {
            union { u32 wd[4]; bhalf8 v; } pu;
            pu.wd[0] = pack2(Sc[2*kc    ][0], Sc[2*kc    ][1]);
            pu.wd[1] = pack2(Sc[2*kc    ][2], Sc[2*kc    ][3]);
            pu.wd[2] = pack2(Sc[2*kc + 1][0], Sc[2*kc + 1][1]);
            pu.wd[3] = pack2(Sc[2*kc + 1][2], Sc[2*kc + 1][3]);
            const bhalf8 pa = pu.v;
            #pragma unroll
            for (int c2 = 0; c2 < 4; ++c2) {
                bhalf8 bv = *(const bhalf8*)&vsT[(16*c2 + n16) * 136 + kc*32 + q4*8];
                O[c2] = __builtin_amdgcn_mfma_f32_16x16x32_bf16(pa, bv, O[c2], 0, 0, 0);
            }
        }

        kc0 = kn0; vc0 = vn0; vc1 = vn1;
    }

    // Epilogue: broadcast l from row-owner lanes (q = q4*4+r lives in lane q).
    const int b = bh >> 4, h = bh & 15;
    float lb[4];
    #pragma unroll
    for (int r = 0; r < 4; ++r) lb[r] = __shfl(lrow, q4*4 + r, 64);
    #pragma unroll
    for (int r = 0; r < 4; ++r) {
        const float rl = 1.0f / lb[r];
        const int t = t0 + w*16 + q4*4 + r;
        #pragma unroll
        for (int c2 = 0; c2 < 4; ++c2)
            y[((size_t)b * T_ + t) * D_ + h * DH_ + 16*c2 + n16] = tob(O[c2][r] * rl);
    }
}

// ---------------------------------------------------------------------------
// Kernel 3 (R16): MFMA out-gemm  yb(4096,1024) @ WoT^T -> out fp32.
// 64x64 tile, gload16 staging. Grid (16,64) = 1024 blocks = 4/CU.
// ---------------------------------------------------------------------------
__global__ __launch_bounds__(256, 4) void out_gemm_mfma(
    const u16* __restrict__ yb, const u16* __restrict__ WoT,
    float* __restrict__ out)
{
    __shared__ __align__(16) u16 As[64 * 64];   // 8192 B, linear
    __shared__ __align__(16) u16 Bs[64 * 64];   // 8192 B, linear
    const int tid  = threadIdx.x;
    const int lane = tid & 63;
    const int w    = tid >> 6;
    const int n16  = lane & 15;
    const int q4   = lane >> 4;
    const int wx   = w & 1;          // n-half (32 cols)
    const int wy   = w >> 1;         // m-half (32 rows)
    const int bm   = blockIdx.y * 64;
    const int bn   = blockIdx.x * 64;
    const int lrow = lane >> 3;
    const int lcol = (lane & 7) * 8;

    floatx4 acc[2][2];
    #pragma unroll
    for (int i = 0; i < 2; ++i)
        #pragma unroll
        for (int j = 0; j < 2; ++j) acc[i][j] = (floatx4)(0.f);

    for (int kt = 0; kt < D_; kt += 64) {
        #pragma unroll
        for (int i = 0; i < 2; ++i) {
            const int r0 = w*16 + i*8;
            gload16(yb  + (size_t)(bm + r0 + lrow) * D_ + kt + lcol, &As[r0 * 64]);
            gload16(WoT + (size_t)(bn + r0 + lrow) * D_ + kt + lcol, &Bs[r0 * 64]);
        }
        __syncthreads();
        #pragma unroll
        for (int kk = 0; kk < 2; ++kk) {
            bhalf8 a[2], b[2];
            #pragma unroll
            for (int mi = 0; mi < 2; ++mi)
                a[mi] = *(const bhalf8*)&As[(wy*32 + mi*16 + n16) * 64 + kk*32 + q4*8];
            #pragma unroll
            for (int ni = 0; ni < 2; ++ni)
                b[ni] = *(const bhalf8*)&Bs[(wx*32 + ni*16 + n16) * 64 + kk*32 + q4*8];
            #pragma unroll
            for (int mi = 0; mi < 2; ++mi)
                #pragma unroll
                for (int ni = 0; ni < 2; ++ni)
                    acc[mi][ni] = __builtin_amdgcn_mfma_f32_16x16x32_bf16(
                        a[mi], b[ni], acc[mi][ni], 0, 0, 0);
        }
        __syncthreads();
    }

    #pragma unroll
    for (int mi = 0; mi < 2; ++mi) {
        #pragma unroll
        for (int rr = 0; rr < 4; ++rr) {
            const int row = bm + wy*32 + mi*16 + q4*4 + rr;
            #pragma unroll
            for (int ni = 0; ni < 2; ++ni) {
                const int col = bn + wx*32 + ni*16 + n16;
                out[(size_t)row * D_ + col] = acc[mi][ni][rr];
            }
        }
    }
}

// ---------------------------------------------------------------------------
extern "C" void kernel_launch(void* const* d_in, const int* in_sizes, int n_in,
                              void* d_out, int out_size, void* d_ws, size_t ws_size,
                              hipStream_t stream)
{
    (void)out_size; (void)ws_size;
    const void* in_x = nullptr; const void* in_wqkv = nullptr;
    const void* in_wq = nullptr; const void* in_wk = nullptr;
    const void* in_core = nullptr; const void* in_wo = nullptr;
    for (int i = 0; i < n_in; ++i) {
        const int s = in_sizes[i];
        if      (s == BT_*D_)     { if (!in_x)    in_x    = d_in[i]; }
        else if (s == D_*3*D_)    { if (!in_wqkv) in_wqkv = d_in[i]; }
        else if (s == H_*DH_*R_)  { if (!in_wq)   in_wq   = d_in[i]; else if (!in_wk) in_wk = d_in[i]; }
        else if (s == H_*R_)      { if (!in_core) in_core = d_in[i]; }
        else if (s == D_*D_)      { if (!in_wo)   in_wo   = d_in[i]; }
    }
    if (!in_x)    in_x    = d_in[0];
    if (!in_wqkv) in_wqkv = d_in[1];
    if (!in_wq)   in_wq   = d_in[2];
    if (!in_wk)   in_wk   = d_in[3];
    if (!in_core) in_core = d_in[4];
    if (!in_wo)   in_wo   = d_in[5];

    float* out = (float*)d_out;

    char* ws    = (char*)d_ws;
    u16*  xb    = (u16*)(ws + WSB_XB);
    u16*  WcatT = (u16*)(ws + WSB_WCATT);
    u16*  ql    = (u16*)(ws + WSB_QL);
    u16*  kl    = (u16*)(ws + WSB_KL);
    u16*  v_t   = (u16*)(ws + WSB_VT);
    u16*  yb    = (u16*)(ws + WSB_YB);
    u16*  WoT   = (u16*)(ws + WSB_WOT);

    convert_fused<<<2560, 256, 0, stream>>>(in_x, xb, in_wqkv, in_wo, WcatT, WoT);
    fold_mfma<<<dim3(8, 16), 256, 0, stream>>>(in_wqkv, in_wq, in_wk, in_core, WcatT, in_x);
    gemm1_mfma<<<dim3(32, 32), 256, 0, stream>>>(xb, WcatT, ql, kl, v_t);
    attn_kernel<<<dim3(32, 16), 512, 0, stream>>>(ql, kl, v_t, yb);
    out_gemm_mfma<<<dim3(16, 64), 256, 0, stream>>>(yb, WoT, out);
}